// Round 6
// baseline (244.554 us; speedup 1.0000x reference)
//
#include <hip/hip_runtime.h>
#include <math.h>

#define NIN 64
#define CAP 16
#define GSEG 250
#define POOL_SPLIT 16
#define CH 2048            // edges per work-queue chunk

__device__ __forceinline__ float wave_reduce_sum(float v) {
    #pragma unroll
    for (int off = 32; off > 0; off >>= 1) v += __shfl_xor(v, off);
    return v;
}

__device__ __forceinline__ unsigned short f2bf(float f) {
    unsigned int u = __float_as_uint(f);
    u += 0x7FFFu + ((u >> 16) & 1u);   // round-to-nearest-even
    return (unsigned short)(u >> 16);
}
__device__ __forceinline__ float bf2f(unsigned short h) {
    return __uint_as_float(((unsigned int)h) << 16);
}

// 15-bit float for w in (0,1]: 5-bit exp, 10-bit mantissa.
__device__ __forceinline__ unsigned int f15enc(float w) {
    unsigned int u = __float_as_uint(w);           // w >= 0
    u += 0x0FFFu + ((u >> 13) & 1u);               // RNE to 10-bit mantissa
    int e5 = (int)(u >> 23) - 96;
    if (e5 <= 0) return 0u;                        // underflow -> 0
    unsigned int m = (u >> 13) & 0x3FFu;
    if (e5 > 31) { e5 = 31; m = 0x3FFu; }
    return ((unsigned int)e5 << 10) | m;
}
__device__ __forceinline__ float f15dec(unsigned int f) {
    if (f == 0u) return 0.0f;
    return __uint_as_float((((f >> 10) + 96u) << 23) | ((f & 0x3FFu) << 13));
}

__device__ __forceinline__ int xcc_id() {
    int x;
    asm volatile("s_getreg_b32 %0, hwreg(HW_REG_XCC_ID)" : "=s"(x));
    return x & 7;
}

// shard-major per-node index: all nodes of shard s live in their own 64B lines
__device__ __forceinline__ int shidx(int c, int np8) {
    return (c & 7) * np8 + (c >> 3);
}

// init: x16 = bf16(x), deg_sh = 1 (self-loop), cnt_sh = 0, out = 0, bounds = 0,
// queue counters = 0, ovf_cnt = 0.  NOTE: aggf NOT zeroed (k_ovf_zero does rows).
__global__ void k_init(ushort4* __restrict__ x164, const float4* __restrict__ x4,
                       float* __restrict__ deg_sh, int* __restrict__ cnt_sh,
                       float* __restrict__ out, int* __restrict__ gstart,
                       int* __restrict__ gend, int* __restrict__ qnext,
                       int* __restrict__ ovf_cnt, int n, int np8) {
    int i = blockIdx.x * blockDim.x + threadIdx.x;
    int tot = n * (NIN / 4);
    if (i < tot) {
        float4 v = x4[i];
        ushort4 h;
        h.x = f2bf(v.x); h.y = f2bf(v.y); h.z = f2bf(v.z); h.w = f2bf(v.w);
        x164[i] = h;
    }
    int ntot = 8 * np8;
    if (i < ntot) { deg_sh[i] = 1.0f; cnt_sh[i] = 0; }
    if (i < GSEG * NIN) out[i] = 0.0f;
    if (i < GSEG) { gstart[i] = 0; gend[i] = 0; }
    if (i < 8) qnext[i] = 0;
    if (i == 0) *ovf_cnt = 0;
}

// XCD-pinned fill: block drains the work queue of its OWN XCD (shard q == xcc),
// processing only edges with (col & 7) == q, then steals from other queues
// (correct under any block->XCD mapping; fast when queue q stays local).
// Node c's ELL line + its deg/cnt line are then written by one XCD only.
__global__ void __launch_bounds__(256)
k_fill(const int* __restrict__ row, const int* __restrict__ col,
       const float* __restrict__ ew, float* __restrict__ deg_sh,
       int* __restrict__ cnt_sh, unsigned int* __restrict__ ell,
       int2* __restrict__ ovf, int* __restrict__ ovf_cnt,
       int* __restrict__ qnext, int e, int nchunks, int np8) {
    int xcc = xcc_id();
    __shared__ int sidx;
    for (int pass = 0; pass < 8; ++pass) {
        int q = (xcc + pass) & 7;
        while (true) {
            if (threadIdx.x == 0) sidx = atomicAdd(&qnext[q], 1);
            __syncthreads();
            int chunk = sidx;
            __syncthreads();
            if (chunk >= nchunks) break;
            int base = chunk * CH;
            int end = base + CH; if (end > e) end = e;
            for (int i = base + (int)threadIdx.x; i < end; i += 256) {
                int c = col[i];
                if ((c & 7) != q) continue;
                int r = row[i];
                float w0 = ew[i];
                int cs = q * np8 + (c >> 3);
                atomicAdd(&deg_sh[cs], w0);
                unsigned int p = ((unsigned int)r << 15) | f15enc(w0);
                int slot = atomicAdd(&cnt_sh[cs], 1);
                if (slot < CAP) {
                    ell[(size_t)c * CAP + slot] = p;
                } else {
                    int oi = atomicAdd(ovf_cnt, 1);
                    ovf[oi] = make_int2(c, (int)p);
                }
            }
        }
    }
}

// fused: deg_sh -> dinv (rsqrt) over shard-major array, and segment bounds
__global__ void k_node(float* __restrict__ deg_sh, const int* __restrict__ seg,
                       int* __restrict__ gstart, int* __restrict__ gend,
                       int n, int np8) {
    int i = blockIdx.x * blockDim.x + threadIdx.x;
    int ntot = 8 * np8;
    if (i < ntot) deg_sh[i] = rsqrtf(deg_sh[i]);   // deg >= 1 always
    if (i >= n) return;
    int s = seg[i];
    if (i == 0 || seg[i - 1] != s) gstart[s] = i;
    if (i == n - 1 || seg[i + 1] != s) gend[s] = i + 1;
}

// Zero aggf rows referenced by overflow entries (redundant zeroes benign).
__global__ void k_ovf_zero(const int2* __restrict__ ovf, const int* __restrict__ ovf_cnt,
                           float* __restrict__ aggf) {
    int nov = *ovf_cnt;
    int wid = (int)((blockIdx.x * (size_t)blockDim.x + threadIdx.x) >> 6);
    int lane = threadIdx.x & 63;
    int nw = (int)((gridDim.x * (size_t)blockDim.x) >> 6);
    for (int i = wid; i < nov; i += nw) {
        aggf[(size_t)ovf[i].x * NIN + lane] = 0.0f;
    }
}

// Replay overflow edges (slot >= CAP) into f32 aggf. One wave per entry.
__global__ void k_ovf(const int2* __restrict__ ovf, const int* __restrict__ ovf_cnt,
                      const float* __restrict__ dinv_sh, const ushort* __restrict__ x16,
                      float* __restrict__ aggf, int np8) {
    int nov = *ovf_cnt;
    int wid = (int)((blockIdx.x * (size_t)blockDim.x + threadIdx.x) >> 6);
    int lane = threadIdx.x & 63;
    int nw = (int)((gridDim.x * (size_t)blockDim.x) >> 6);
    for (int i = wid; i < nov; i += nw) {
        int2 ov = ovf[i];
        int c = ov.x;
        unsigned int p = (unsigned int)ov.y;
        int r = (int)(p >> 15);
        float w = f15dec(p & 0x7FFFu) * dinv_sh[shidx(r, np8)] * dinv_sh[shidx(c, np8)];
        atomicAdd(&aggf[(size_t)c * NIN + lane], w * bf2f(x16[(size_t)r * NIN + lane]));
    }
}

// Quarter-wave gather: 4 nodes/wave, 16 lanes/node, ushort4 per lane.
__global__ void __launch_bounds__(256)
k_gather(const ushort* __restrict__ x16, const float* __restrict__ dinv_sh,
         const int* __restrict__ cnt_sh, const unsigned int* __restrict__ ell,
         const float* __restrict__ aggf, ushort* __restrict__ agg16,
         const float* __restrict__ Wp, const float* __restrict__ bp,
         float* __restrict__ score, int n, int np8) {
    int wid = (int)((blockIdx.x * (size_t)blockDim.x + threadIdx.x) >> 6);
    int lane = threadIdx.x & 63;
    int q = lane >> 4, l = lane & 15;
    int c0 = wid * 4;
    if (c0 >= n) return;
    int c = c0 + q;
    bool valid = c < n;
    int cc = valid ? c : (n - 1);
    int ccs = shidx(cc, np8);

    int cr = cnt_sh[ccs];
    int m = valid ? (cr < CAP ? cr : CAP) : 0;
    float di = dinv_sh[ccs];

    // lane l holds slot l of its node's ELL row (wave: 4 nodes x 64B contiguous)
    unsigned int pe = ell[(size_t)cc * CAP + l];
    int pr = (int)(pe >> 15);
    float pw = f15dec(pe & 0x7FFFu) * dinv_sh[shidx(pr, np8)];  // w' = dinv[r]*ew

    const ushort4* xv4 = (const ushort4*)x16;
    ushort4 xs = xv4[(size_t)cc * 16 + l];
    float a0 = di * bf2f(xs.x), a1 = di * bf2f(xs.y);
    float a2 = di * bf2f(xs.z), a3 = di * bf2f(xs.w);

    int base = lane & 48;   // first lane of this quarter
    #pragma unroll
    for (int k = 0; k < 8; ++k) {
        int rk = __shfl(pr, base + k);
        float wk = __shfl(pw, base + k);
        bool v = k < m;
        int r = v ? rk : 0;
        float w = v ? wk : 0.0f;
        ushort4 xr = xv4[(size_t)r * 16 + l];
        a0 = fmaf(w, bf2f(xr.x), a0);
        a1 = fmaf(w, bf2f(xr.y), a1);
        a2 = fmaf(w, bf2f(xr.z), a2);
        a3 = fmaf(w, bf2f(xr.w), a3);
    }
    if (__any(m > 8)) {
        #pragma unroll
        for (int k = 8; k < CAP; ++k) {
            int rk = __shfl(pr, base + k);
            float wk = __shfl(pw, base + k);
            bool v = k < m;
            int r = v ? rk : 0;
            float w = v ? wk : 0.0f;
            ushort4 xr = xv4[(size_t)r * 16 + l];
            a0 = fmaf(w, bf2f(xr.x), a0);
            a1 = fmaf(w, bf2f(xr.y), a1);
            a2 = fmaf(w, bf2f(xr.z), a2);
            a3 = fmaf(w, bf2f(xr.w), a3);
        }
    }
    a0 *= di; a1 *= di; a2 *= di; a3 *= di;

    if (valid && cr > CAP) {
        const float4* af4 = (const float4*)aggf;
        float4 fo = af4[(size_t)cc * 16 + l];
        a0 += fo.x; a1 += fo.y; a2 += fo.z; a3 += fo.w;
    }

    if (valid) {
        ushort4 ho;
        ho.x = f2bf(a0); ho.y = f2bf(a1); ho.z = f2bf(a2); ho.w = f2bf(a3);
        ((ushort4*)agg16)[(size_t)cc * 16 + l] = ho;
    }

    const float4* wp4 = (const float4*)Wp;
    float4 wv = wp4[l];
    float part = a0 * wv.x + a1 * wv.y + a2 * wv.z + a3 * wv.w;
    part += __shfl_xor(part, 1);
    part += __shfl_xor(part, 2);
    part += __shfl_xor(part, 4);
    part += __shfl_xor(part, 8);
    if (l == 0 && valid) score[c] = part + bp[0];
}

// POOL_SPLIT blocks per graph. Fused per-graph softmax; W column in 16 NAMED
// float4s; node agg row staged via LDS broadcast; 4 FMA chains; prefetch.
#define WLOAD(i) float4 wq##i = make_float4(We[(4*(i)+0)*NIN+lane], We[(4*(i)+1)*NIN+lane], \
                                            We[(4*(i)+2)*NIN+lane], We[(4*(i)+3)*NIN+lane]);
#define WSTEP(i) { float4 av = *(const float4*)&als[wv][4*(i)]; \
    e0 = fmaf(av.x, wq##i.x, e0); e1 = fmaf(av.y, wq##i.y, e1); \
    e2 = fmaf(av.z, wq##i.z, e2); e3 = fmaf(av.w, wq##i.w, e3); }

__global__ void __launch_bounds__(256)
k_pool(const ushort* __restrict__ agg16, const float* __restrict__ score,
       const float* __restrict__ We, const float* __restrict__ be,
       const int* __restrict__ gstart, const int* __restrict__ gend,
       float* __restrict__ out) {
    int g = blockIdx.x / POOL_SPLIT;
    int p = blockIdx.x % POOL_SPLIT;
    int tid = threadIdx.x;
    int wv = tid >> 6, lane = tid & 63;
    int s = gstart[g], e = gend[g];

    __shared__ float red[4];
    __shared__ float bc;

    float mx = -3.402823466e38f;
    for (int i = s + tid; i < e; i += 256) mx = fmaxf(mx, score[i]);
    #pragma unroll
    for (int off = 32; off > 0; off >>= 1) mx = fmaxf(mx, __shfl_xor(mx, off));
    if (lane == 0) red[wv] = mx;
    __syncthreads();
    if (tid == 0) bc = fmaxf(fmaxf(red[0], red[1]), fmaxf(red[2], red[3]));
    __syncthreads();
    float m = bc;
    __syncthreads();

    float sm = 0.0f;
    for (int i = s + tid; i < e; i += 256) sm += __expf(score[i] - m);
    sm = wave_reduce_sum(sm);
    if (lane == 0) red[wv] = sm;
    __syncthreads();
    if (tid == 0) bc = red[0] + red[1] + red[2] + red[3];
    __syncthreads();
    float invz = (bc > 0.0f) ? 1.0f / bc : 0.0f;

    WLOAD(0) WLOAD(1) WLOAD(2) WLOAD(3) WLOAD(4) WLOAD(5) WLOAD(6) WLOAD(7)
    WLOAD(8) WLOAD(9) WLOAD(10) WLOAD(11) WLOAD(12) WLOAD(13) WLOAD(14) WLOAD(15)
    float bj = be[lane];

    __shared__ float als[4][NIN];
    __shared__ float part[4][NIN];

    const int stride = POOL_SPLIT * 4;
    int n = s + p * 4 + wv;
    float acc = 0.0f;

    float a_cur = 0.0f, sw_cur = 0.0f;
    if (n < e) {
        a_cur = bf2f(agg16[(size_t)n * NIN + lane]);
        sw_cur = __expf(score[n] - m) * invz;
    }
    while (n < e) {
        int nn = n + stride;
        bool vn = nn < e;
        int ni = vn ? nn : n;
        float a_nxt = bf2f(agg16[(size_t)ni * NIN + lane]);   // prefetch
        float sw_nxt = __expf(score[ni] - m) * invz;

        als[wv][lane] = a_cur;
        float e0 = bj, e1 = 0.0f, e2 = 0.0f, e3 = 0.0f;
        WSTEP(0) WSTEP(1) WSTEP(2) WSTEP(3) WSTEP(4) WSTEP(5) WSTEP(6) WSTEP(7)
        WSTEP(8) WSTEP(9) WSTEP(10) WSTEP(11) WSTEP(12) WSTEP(13) WSTEP(14) WSTEP(15)
        float emb = fmaxf(e0 + e1 + e2 + e3, 0.0f);
        acc = fmaf(sw_cur, emb, acc);

        a_cur = a_nxt; sw_cur = sw_nxt;
        n = nn;
    }
    part[wv][lane] = acc;
    __syncthreads();
    if (wv == 0) {
        float r = part[0][lane] + part[1][lane] + part[2][lane] + part[3][lane];
        atomicAdd(&out[(size_t)g * NIN + lane], r);
    }
}

extern "C" void kernel_launch(void* const* d_in, const int* in_sizes, int n_in,
                              void* d_out, int out_size, void* d_ws, size_t ws_size,
                              hipStream_t stream) {
    const float* x  = (const float*)d_in[0];
    const float* We = (const float*)d_in[1];
    const float* be = (const float*)d_in[2];
    const float* Wp = (const float*)d_in[3];
    const float* bp = (const float*)d_in[4];
    const float* ew = (const float*)d_in[5];
    const int* eidx = (const int*)d_in[6];
    const int* seg  = (const int*)d_in[7];

    int N = in_sizes[0] / NIN;
    int E = in_sizes[5];
    const int* row = eidx;
    const int* col = eidx + E;
    int np8 = (N + 7) / 8;

    char* w = (char*)d_ws;
    auto alloc = [&](size_t bytes) {
        char* p = w;
        w += (bytes + 255) & ~(size_t)255;
        return p;
    };
    float*          aggf    = (float*)alloc((size_t)N * NIN * sizeof(float));
    unsigned short* x16     = (unsigned short*)alloc((size_t)N * NIN * sizeof(short));
    unsigned short* agg16   = (unsigned short*)alloc((size_t)N * NIN * sizeof(short));
    float*          deg_sh  = (float*)alloc((size_t)np8 * 8 * sizeof(float));
    int*            cnt_sh  = (int*)  alloc((size_t)np8 * 8 * sizeof(int));
    unsigned int*   ell     = (unsigned int*)alloc((size_t)N * CAP * sizeof(unsigned int));
    int2*           ovf     = (int2*) alloc((size_t)E * sizeof(int2));
    int*            ovf_cnt = (int*)  alloc(256);
    int*            qnext   = (int*)  alloc(256);
    float*          score   = (float*)alloc((size_t)N * sizeof(float));
    int*            gstart  = (int*)  alloc(GSEG * sizeof(int));
    int*            gend    = (int*)  alloc(GSEG * sizeof(int));
    float* out = (float*)d_out;

    int b = 256;
    int g_init   = (N * (NIN / 4) + b - 1) / b;
    int nchunks  = (E + CH - 1) / CH;
    int g_fill   = 1024;
    int g_nodes  = ((np8 * 8 > N ? np8 * 8 : N) + b - 1) / b;
    int nwaves   = (N + 3) / 4;
    int g_gather = (nwaves + 3) / 4;

    k_init<<<g_init, b, 0, stream>>>((ushort4*)x16, (const float4*)x, deg_sh, cnt_sh,
                                     out, gstart, gend, qnext, ovf_cnt, N, np8);
    k_fill<<<g_fill, b, 0, stream>>>(row, col, ew, deg_sh, cnt_sh, ell, ovf, ovf_cnt,
                                     qnext, E, nchunks, np8);
    k_node<<<g_nodes, b, 0, stream>>>(deg_sh, seg, gstart, gend, N, np8);
    k_ovf_zero<<<64, b, 0, stream>>>(ovf, ovf_cnt, aggf);
    k_ovf<<<64, b, 0, stream>>>(ovf, ovf_cnt, deg_sh, x16, aggf, np8);
    k_gather<<<g_gather, b, 0, stream>>>(x16, deg_sh, cnt_sh, ell, aggf, agg16,
                                         Wp, bp, score, N, np8);
    k_pool<<<GSEG * POOL_SPLIT, b, 0, stream>>>(agg16, score, We, be, gstart, gend, out);
}

// Round 7
// 151.887 us; speedup vs baseline: 1.6101x; 1.6101x over previous
//
#include <hip/hip_runtime.h>
#include <math.h>

#define NIN 64
#define CAP 16
#define GSEG 250
#define POOL_SPLIT 16
#define BND 256            // nodes per bucket
#define RCAP 640           // records per (xcd,bucket) region (mean ~255)

__device__ __forceinline__ float wave_reduce_sum(float v) {
    #pragma unroll
    for (int off = 32; off > 0; off >>= 1) v += __shfl_xor(v, off);
    return v;
}

__device__ __forceinline__ unsigned short f2bf(float f) {
    unsigned int u = __float_as_uint(f);
    u += 0x7FFFu + ((u >> 16) & 1u);   // round-to-nearest-even
    return (unsigned short)(u >> 16);
}
__device__ __forceinline__ float bf2f(unsigned short h) {
    return __uint_as_float(((unsigned int)h) << 16);
}

// 15-bit float for w in (0,1]: 5-bit exp, 10-bit mantissa.
__device__ __forceinline__ unsigned int f15enc(float w) {
    unsigned int u = __float_as_uint(w);           // w >= 0
    u += 0x0FFFu + ((u >> 13) & 1u);               // RNE to 10-bit mantissa
    int e5 = (int)(u >> 23) - 96;
    if (e5 <= 0) return 0u;                        // underflow -> 0
    unsigned int m = (u >> 13) & 0x3FFu;
    if (e5 > 31) { e5 = 31; m = 0x3FFu; }
    return ((unsigned int)e5 << 10) | m;
}
__device__ __forceinline__ float f15dec(unsigned int f) {
    if (f == 0u) return 0.0f;
    return __uint_as_float((((f >> 10) + 96u) << 23) | ((f & 0x3FFu) << 13));
}

__device__ __forceinline__ int xcc_id() {
    int x;
    asm volatile("s_getreg_b32 %0, hwreg(HW_REG_XCC_ID)" : "=s"(x));
    return x & 7;
}

// init: x16 = bf16(x), out = 0, bounds = 0, bin counters = 0, spill/ovf counters = 0
__global__ void k_init(ushort4* __restrict__ x164, const float4* __restrict__ x4,
                       float* __restrict__ out, int* __restrict__ gstart,
                       int* __restrict__ gend, int* __restrict__ bincnt,
                       int* __restrict__ spill_cnt, int* __restrict__ ovf_cnt,
                       int n, int nb) {
    int i = blockIdx.x * blockDim.x + threadIdx.x;
    int tot = n * (NIN / 4);
    if (i < tot) {
        float4 v = x4[i];
        ushort4 h;
        h.x = f2bf(v.x); h.y = f2bf(v.y); h.z = f2bf(v.z); h.w = f2bf(v.w);
        x164[i] = h;
    }
    if (i < GSEG * NIN) out[i] = 0.0f;
    if (i < GSEG) { gstart[i] = 0; gend[i] = 0; }
    if (i < 8 * nb) bincnt[i] = 0;
    if (i == 0) { *spill_cnt = 0; *ovf_cnt = 0; }
}

// Phase A: bin edges by destination bucket into the region of the XCD the
// block ACTUALLY runs on (xcc_id read; any value is correct, locality free).
// Append-tail lines are re-touched every ~60ns -> resident until full ->
// written once. Kills the one-line-eviction-per-edge write amplification.
__global__ void __launch_bounds__(256)
k_bin(const int* __restrict__ row, const int* __restrict__ col,
      const float* __restrict__ ew, int* __restrict__ bincnt,
      uint2* __restrict__ bins, uint2* __restrict__ spill,
      int* __restrict__ spill_cnt, int e, int nb) {
    int i = blockIdx.x * 256 + threadIdx.x;
    int x = xcc_id();
    if (i >= e) return;
    int c = col[i], r = row[i];
    unsigned int w15 = f15enc(ew[i]);
    int b = c >> 8;
    int slot = atomicAdd(&bincnt[x * nb + b], 1);
    if (slot < RCAP) {
        uint2 rec;
        rec.x = (unsigned int)r;
        rec.y = ((unsigned int)(c & (BND - 1)) << 15) | w15;
        bins[((size_t)(x * nb + b)) * RCAP + slot] = rec;
    } else {
        int si = atomicAdd(spill_cnt, 1);
        spill[si] = make_uint2((unsigned int)r, ((unsigned int)c << 15) | w15);
    }
}

// Phase B: one block per bucket. Assemble 256 ELL rows + deg + cnt in LDS,
// then burst-write contiguous 16KB. All random scatter stays on-chip.
__global__ void __launch_bounds__(256)
k_build(const uint2* __restrict__ bins, const int* __restrict__ bincnt,
        unsigned int* __restrict__ ell, float* __restrict__ deg,
        int* __restrict__ cnt, int2* __restrict__ ovf, int* __restrict__ ovf_cnt,
        int n, int nb) {
    int b = blockIdx.x;
    int c0 = b << 8;
    int nn = n - c0; if (nn > BND) nn = BND;
    __shared__ unsigned int tile[BND * CAP];   // 16 KB
    __shared__ float sdeg[BND];
    __shared__ int scnt[BND];
    int tid = threadIdx.x;
    sdeg[tid] = 0.0f; scnt[tid] = 0;
    for (int i = tid; i < BND * CAP; i += 256) tile[i] = 0u;
    __syncthreads();
    for (int x = 0; x < 8; ++x) {
        int len = bincnt[x * nb + b];
        if (len > RCAP) len = RCAP;
        const uint2* base = bins + ((size_t)(x * nb + b)) * RCAP;
        for (int i = tid; i < len; i += 256) {
            uint2 rec = base[i];
            int cl = (int)((rec.y >> 15) & (BND - 1));
            unsigned int w15 = rec.y & 0x7FFFu;
            atomicAdd(&sdeg[cl], f15dec(w15));
            int slot = atomicAdd(&scnt[cl], 1);
            unsigned int p = (rec.x << 15) | w15;
            if (slot < CAP) {
                tile[cl * CAP + slot] = p;
            } else {
                int oi = atomicAdd(ovf_cnt, 1);
                ovf[oi] = make_int2(c0 + cl, (int)p);
            }
        }
    }
    __syncthreads();
    for (int i = tid; i < nn * CAP; i += 256)
        ell[(size_t)c0 * CAP + i] = tile[i];
    if (tid < nn) {
        deg[c0 + tid] = sdeg[tid] + 1.0f;   // + self-loop
        cnt[c0 + tid] = scnt[tid];
    }
}

// Region-overflow replay (expected ~0 entries). Random atomics, slow path.
__global__ void k_spill(const uint2* __restrict__ spill, const int* __restrict__ spill_cnt,
                        float* __restrict__ deg, int* __restrict__ cnt,
                        unsigned int* __restrict__ ell, int2* __restrict__ ovf,
                        int* __restrict__ ovf_cnt) {
    int ns = *spill_cnt;
    int i = blockIdx.x * blockDim.x + threadIdx.x;
    int stride = gridDim.x * blockDim.x;
    for (; i < ns; i += stride) {
        uint2 rec = spill[i];
        int c = (int)(rec.y >> 15);
        unsigned int w15 = rec.y & 0x7FFFu;
        atomicAdd(&deg[c], f15dec(w15));
        int slot = atomicAdd(&cnt[c], 1);
        unsigned int p = (rec.x << 15) | w15;
        if (slot < CAP) {
            ell[(size_t)c * CAP + slot] = p;
        } else {
            int oi = atomicAdd(ovf_cnt, 1);
            ovf[oi] = make_int2(c, (int)p);
        }
    }
}

// fused: deg -> dinv (rsqrt), and segment bounds from sorted segment_ids
__global__ void k_node(float* __restrict__ deg, const int* __restrict__ seg,
                       int* __restrict__ gstart, int* __restrict__ gend, int n) {
    int i = blockIdx.x * blockDim.x + threadIdx.x;
    if (i >= n) return;
    deg[i] = rsqrtf(deg[i]);   // deg >= 1 always
    int s = seg[i];
    if (i == 0 || seg[i - 1] != s) gstart[s] = i;
    if (i == n - 1 || seg[i + 1] != s) gend[s] = i + 1;
}

// Zero aggf rows referenced by overflow entries (redundant zeroes benign).
__global__ void k_ovf_zero(const int2* __restrict__ ovf, const int* __restrict__ ovf_cnt,
                           float* __restrict__ aggf) {
    int nov = *ovf_cnt;
    int wid = (int)((blockIdx.x * (size_t)blockDim.x + threadIdx.x) >> 6);
    int lane = threadIdx.x & 63;
    int nw = (int)((gridDim.x * (size_t)blockDim.x) >> 6);
    for (int i = wid; i < nov; i += nw) {
        aggf[(size_t)ovf[i].x * NIN + lane] = 0.0f;
    }
}

// Replay node-degree-overflow edges (slot >= CAP, ~hundreds) into f32 aggf.
__global__ void k_ovf(const int2* __restrict__ ovf, const int* __restrict__ ovf_cnt,
                      const float* __restrict__ dinv, const ushort* __restrict__ x16,
                      float* __restrict__ aggf) {
    int nov = *ovf_cnt;
    int wid = (int)((blockIdx.x * (size_t)blockDim.x + threadIdx.x) >> 6);
    int lane = threadIdx.x & 63;
    int nw = (int)((gridDim.x * (size_t)blockDim.x) >> 6);
    for (int i = wid; i < nov; i += nw) {
        int2 ov = ovf[i];
        int c = ov.x;
        unsigned int p = (unsigned int)ov.y;
        int r = (int)(p >> 15);
        float w = f15dec(p & 0x7FFFu) * dinv[r] * dinv[c];
        atomicAdd(&aggf[(size_t)c * NIN + lane], w * bf2f(x16[(size_t)r * NIN + lane]));
    }
}

// Quarter-wave gather: 4 nodes/wave, 16 lanes/node, ushort4 per lane.
__global__ void __launch_bounds__(256)
k_gather(const ushort* __restrict__ x16, const float* __restrict__ dinv,
         const int* __restrict__ cnt, const unsigned int* __restrict__ ell,
         const float* __restrict__ aggf, ushort* __restrict__ agg16,
         const float* __restrict__ Wp, const float* __restrict__ bp,
         float* __restrict__ score, int n) {
    int wid = (int)((blockIdx.x * (size_t)blockDim.x + threadIdx.x) >> 6);
    int lane = threadIdx.x & 63;
    int q = lane >> 4, l = lane & 15;
    int c0 = wid * 4;
    if (c0 >= n) return;
    int c = c0 + q;
    bool valid = c < n;
    int cc = valid ? c : (n - 1);

    int cr = cnt[cc];
    int m = valid ? (cr < CAP ? cr : CAP) : 0;
    float di = dinv[cc];

    // lane l holds slot l of its node's ELL row (wave: 4 nodes x 64B contiguous)
    unsigned int pe = ell[(size_t)cc * CAP + l];
    int pr = (int)(pe >> 15);
    float pw = f15dec(pe & 0x7FFFu) * dinv[pr];   // w' = dinv[r]*ew

    const ushort4* xv4 = (const ushort4*)x16;
    ushort4 xs = xv4[(size_t)cc * 16 + l];
    float a0 = di * bf2f(xs.x), a1 = di * bf2f(xs.y);
    float a2 = di * bf2f(xs.z), a3 = di * bf2f(xs.w);

    int base = lane & 48;   // first lane of this quarter
    #pragma unroll
    for (int k = 0; k < 8; ++k) {
        int rk = __shfl(pr, base + k);
        float wk = __shfl(pw, base + k);
        bool v = k < m;
        int r = v ? rk : 0;
        float w = v ? wk : 0.0f;
        ushort4 xr = xv4[(size_t)r * 16 + l];
        a0 = fmaf(w, bf2f(xr.x), a0);
        a1 = fmaf(w, bf2f(xr.y), a1);
        a2 = fmaf(w, bf2f(xr.z), a2);
        a3 = fmaf(w, bf2f(xr.w), a3);
    }
    if (__any(m > 8)) {
        #pragma unroll
        for (int k = 8; k < CAP; ++k) {
            int rk = __shfl(pr, base + k);
            float wk = __shfl(pw, base + k);
            bool v = k < m;
            int r = v ? rk : 0;
            float w = v ? wk : 0.0f;
            ushort4 xr = xv4[(size_t)r * 16 + l];
            a0 = fmaf(w, bf2f(xr.x), a0);
            a1 = fmaf(w, bf2f(xr.y), a1);
            a2 = fmaf(w, bf2f(xr.z), a2);
            a3 = fmaf(w, bf2f(xr.w), a3);
        }
    }
    a0 *= di; a1 *= di; a2 *= di; a3 *= di;

    if (valid && cr > CAP) {
        const float4* af4 = (const float4*)aggf;
        float4 fo = af4[(size_t)cc * 16 + l];
        a0 += fo.x; a1 += fo.y; a2 += fo.z; a3 += fo.w;
    }

    if (valid) {
        ushort4 ho;
        ho.x = f2bf(a0); ho.y = f2bf(a1); ho.z = f2bf(a2); ho.w = f2bf(a3);
        ((ushort4*)agg16)[(size_t)cc * 16 + l] = ho;
    }

    const float4* wp4 = (const float4*)Wp;
    float4 wv = wp4[l];
    float part = a0 * wv.x + a1 * wv.y + a2 * wv.z + a3 * wv.w;
    part += __shfl_xor(part, 1);
    part += __shfl_xor(part, 2);
    part += __shfl_xor(part, 4);
    part += __shfl_xor(part, 8);
    if (l == 0 && valid) score[c] = part + bp[0];
}

// POOL_SPLIT blocks per graph. Fused per-graph softmax; W column in 16 NAMED
// float4s; node agg row staged via LDS broadcast; 4 FMA chains; prefetch.
#define WLOAD(i) float4 wq##i = make_float4(We[(4*(i)+0)*NIN+lane], We[(4*(i)+1)*NIN+lane], \
                                            We[(4*(i)+2)*NIN+lane], We[(4*(i)+3)*NIN+lane]);
#define WSTEP(i) { float4 av = *(const float4*)&als[wv][4*(i)]; \
    e0 = fmaf(av.x, wq##i.x, e0); e1 = fmaf(av.y, wq##i.y, e1); \
    e2 = fmaf(av.z, wq##i.z, e2); e3 = fmaf(av.w, wq##i.w, e3); }

__global__ void __launch_bounds__(256)
k_pool(const ushort* __restrict__ agg16, const float* __restrict__ score,
       const float* __restrict__ We, const float* __restrict__ be,
       const int* __restrict__ gstart, const int* __restrict__ gend,
       float* __restrict__ out) {
    int g = blockIdx.x / POOL_SPLIT;
    int p = blockIdx.x % POOL_SPLIT;
    int tid = threadIdx.x;
    int wv = tid >> 6, lane = tid & 63;
    int s = gstart[g], e = gend[g];

    __shared__ float red[4];
    __shared__ float bc;

    float mx = -3.402823466e38f;
    for (int i = s + tid; i < e; i += 256) mx = fmaxf(mx, score[i]);
    #pragma unroll
    for (int off = 32; off > 0; off >>= 1) mx = fmaxf(mx, __shfl_xor(mx, off));
    if (lane == 0) red[wv] = mx;
    __syncthreads();
    if (tid == 0) bc = fmaxf(fmaxf(red[0], red[1]), fmaxf(red[2], red[3]));
    __syncthreads();
    float m = bc;
    __syncthreads();

    float sm = 0.0f;
    for (int i = s + tid; i < e; i += 256) sm += __expf(score[i] - m);
    sm = wave_reduce_sum(sm);
    if (lane == 0) red[wv] = sm;
    __syncthreads();
    if (tid == 0) bc = red[0] + red[1] + red[2] + red[3];
    __syncthreads();
    float invz = (bc > 0.0f) ? 1.0f / bc : 0.0f;

    WLOAD(0) WLOAD(1) WLOAD(2) WLOAD(3) WLOAD(4) WLOAD(5) WLOAD(6) WLOAD(7)
    WLOAD(8) WLOAD(9) WLOAD(10) WLOAD(11) WLOAD(12) WLOAD(13) WLOAD(14) WLOAD(15)
    float bj = be[lane];

    __shared__ float als[4][NIN];
    __shared__ float part[4][NIN];

    const int stride = POOL_SPLIT * 4;
    int n = s + p * 4 + wv;
    float acc = 0.0f;

    float a_cur = 0.0f, sw_cur = 0.0f;
    if (n < e) {
        a_cur = bf2f(agg16[(size_t)n * NIN + lane]);
        sw_cur = __expf(score[n] - m) * invz;
    }
    while (n < e) {
        int nn = n + stride;
        bool vn = nn < e;
        int ni = vn ? nn : n;
        float a_nxt = bf2f(agg16[(size_t)ni * NIN + lane]);   // prefetch
        float sw_nxt = __expf(score[ni] - m) * invz;

        als[wv][lane] = a_cur;
        float e0 = bj, e1 = 0.0f, e2 = 0.0f, e3 = 0.0f;
        WSTEP(0) WSTEP(1) WSTEP(2) WSTEP(3) WSTEP(4) WSTEP(5) WSTEP(6) WSTEP(7)
        WSTEP(8) WSTEP(9) WSTEP(10) WSTEP(11) WSTEP(12) WSTEP(13) WSTEP(14) WSTEP(15)
        float emb = fmaxf(e0 + e1 + e2 + e3, 0.0f);
        acc = fmaf(sw_cur, emb, acc);

        a_cur = a_nxt; sw_cur = sw_nxt;
        n = nn;
    }
    part[wv][lane] = acc;
    __syncthreads();
    if (wv == 0) {
        float r = part[0][lane] + part[1][lane] + part[2][lane] + part[3][lane];
        atomicAdd(&out[(size_t)g * NIN + lane], r);
    }
}

extern "C" void kernel_launch(void* const* d_in, const int* in_sizes, int n_in,
                              void* d_out, int out_size, void* d_ws, size_t ws_size,
                              hipStream_t stream) {
    const float* x  = (const float*)d_in[0];
    const float* We = (const float*)d_in[1];
    const float* be = (const float*)d_in[2];
    const float* Wp = (const float*)d_in[3];
    const float* bp = (const float*)d_in[4];
    const float* ew = (const float*)d_in[5];
    const int* eidx = (const int*)d_in[6];
    const int* seg  = (const int*)d_in[7];

    int N = in_sizes[0] / NIN;
    int E = in_sizes[5];
    const int* row = eidx;
    const int* col = eidx + E;
    int nb = (N + BND - 1) / BND;

    char* w = (char*)d_ws;
    auto alloc = [&](size_t bytes) {
        char* p = w;
        w += (bytes + 255) & ~(size_t)255;
        return p;
    };
    float*          aggf      = (float*)alloc((size_t)N * NIN * sizeof(float));
    unsigned short* x16       = (unsigned short*)alloc((size_t)N * NIN * sizeof(short));
    unsigned short* agg16     = (unsigned short*)alloc((size_t)N * NIN * sizeof(short));
    float*          deg       = (float*)alloc((size_t)N * sizeof(float));
    int*            cnt       = (int*)  alloc((size_t)N * sizeof(int));
    unsigned int*   ell       = (unsigned int*)alloc((size_t)N * CAP * sizeof(unsigned int));
    uint2*          bins      = (uint2*)alloc((size_t)8 * nb * RCAP * sizeof(uint2));
    int*            bincnt    = (int*)  alloc((size_t)8 * nb * sizeof(int));
    uint2*          spill     = (uint2*)alloc((size_t)(E / 2) * sizeof(uint2));
    int*            spill_cnt = (int*)  alloc(256);
    int2*           ovf       = (int2*) alloc((size_t)(E / 2) * sizeof(int2));
    int*            ovf_cnt   = (int*)  alloc(256);
    float*          score     = (float*)alloc((size_t)N * sizeof(float));
    int*            gstart    = (int*)  alloc(GSEG * sizeof(int));
    int*            gend      = (int*)  alloc(GSEG * sizeof(int));
    float* out = (float*)d_out;

    int b = 256;
    int g_init   = (N * (NIN / 4) + b - 1) / b;
    int g_bin    = (E + b - 1) / b;
    int g_nodes  = (N + b - 1) / b;
    int nwaves   = (N + 3) / 4;
    int g_gather = (nwaves + 3) / 4;

    k_init<<<g_init, b, 0, stream>>>((ushort4*)x16, (const float4*)x, out, gstart,
                                     gend, bincnt, spill_cnt, ovf_cnt, N, nb);
    k_bin<<<g_bin, b, 0, stream>>>(row, col, ew, bincnt, bins, spill, spill_cnt, E, nb);
    k_build<<<nb, b, 0, stream>>>(bins, bincnt, ell, deg, cnt, ovf, ovf_cnt, N, nb);
    k_spill<<<16, b, 0, stream>>>(spill, spill_cnt, deg, cnt, ell, ovf, ovf_cnt);
    k_node<<<g_nodes, b, 0, stream>>>(deg, seg, gstart, gend, N);
    k_ovf_zero<<<64, b, 0, stream>>>(ovf, ovf_cnt, aggf);
    k_ovf<<<64, b, 0, stream>>>(ovf, ovf_cnt, deg, x16, aggf);
    k_gather<<<g_gather, b, 0, stream>>>(x16, deg, cnt, ell, aggf, agg16, Wp, bp, score, N);
    k_pool<<<GSEG * POOL_SPLIT, b, 0, stream>>>(agg16, score, We, be, gstart, gend, out);
}

// Round 8
// 122.891 us; speedup vs baseline: 1.9900x; 1.2360x over previous
//
#include <hip/hip_runtime.h>
#include <math.h>

#define NIN 64
#define CAP 16
#define GSEG 250
#define POOL_SPLIT 16
#define BND 256            // nodes per bucket
#define RCAP 640           // records per (xcd,bucket) region (mean ~255)
#define CSTRIDE 16         // ints per bin counter: one counter per 64B line

__device__ __forceinline__ float wave_reduce_sum(float v) {
    #pragma unroll
    for (int off = 32; off > 0; off >>= 1) v += __shfl_xor(v, off);
    return v;
}

__device__ __forceinline__ unsigned short f2bf(float f) {
    unsigned int u = __float_as_uint(f);
    u += 0x7FFFu + ((u >> 16) & 1u);   // round-to-nearest-even
    return (unsigned short)(u >> 16);
}
__device__ __forceinline__ float bf2f(unsigned short h) {
    return __uint_as_float(((unsigned int)h) << 16);
}

// 15-bit float for w in (0,1]: 5-bit exp, 10-bit mantissa.
__device__ __forceinline__ unsigned int f15enc(float w) {
    unsigned int u = __float_as_uint(w);           // w >= 0
    u += 0x0FFFu + ((u >> 13) & 1u);               // RNE to 10-bit mantissa
    int e5 = (int)(u >> 23) - 96;
    if (e5 <= 0) return 0u;                        // underflow -> 0
    unsigned int m = (u >> 13) & 0x3FFu;
    if (e5 > 31) { e5 = 31; m = 0x3FFu; }
    return ((unsigned int)e5 << 10) | m;
}
__device__ __forceinline__ float f15dec(unsigned int f) {
    if (f == 0u) return 0.0f;
    return __uint_as_float((((f >> 10) + 96u) << 23) | ((f & 0x3FFu) << 13));
}

__device__ __forceinline__ int xcc_id() {
    int x;
    asm volatile("s_getreg_b32 %0, hwreg(HW_REG_XCC_ID)" : "=s"(x));
    return x & 7;
}

// init: x16 = bf16(x), out = 0, bounds = 0, bin counters = 0, spill/ovf counters = 0
__global__ void k_init(ushort4* __restrict__ x164, const float4* __restrict__ x4,
                       float* __restrict__ out, int* __restrict__ gstart,
                       int* __restrict__ gend, int* __restrict__ bincnt,
                       int* __restrict__ spill_cnt, int* __restrict__ ovf_cnt,
                       int n, int nb) {
    int i = blockIdx.x * blockDim.x + threadIdx.x;
    int tot = n * (NIN / 4);
    if (i < tot) {
        float4 v = x4[i];
        ushort4 h;
        h.x = f2bf(v.x); h.y = f2bf(v.y); h.z = f2bf(v.z); h.w = f2bf(v.w);
        x164[i] = h;
    }
    if (i < GSEG * NIN) out[i] = 0.0f;
    if (i < GSEG) { gstart[i] = 0; gend[i] = 0; }
    if (i < 8 * nb * CSTRIDE) bincnt[i] = 0;
    if (i == 0) { *spill_cnt = 0; *ovf_cnt = 0; }
}

// Phase A: bin edges by destination bucket into the region of the XCD the
// block ACTUALLY runs on. Counters padded to one per 64B line: device-scope
// atomics serialize per-line at the coherence point, so line-sharing was the
// R6 k_bin bottleneck (16 counters/line -> ~4000 serialized RMW/line).
__global__ void __launch_bounds__(256)
k_bin(const int* __restrict__ row, const int* __restrict__ col,
      const float* __restrict__ ew, int* __restrict__ bincnt,
      uint2* __restrict__ bins, uint2* __restrict__ spill,
      int* __restrict__ spill_cnt, int e, int nb) {
    int i = blockIdx.x * 256 + threadIdx.x;
    int x = xcc_id();
    if (i >= e) return;
    int c = col[i], r = row[i];
    unsigned int w15 = f15enc(ew[i]);
    int b = c >> 8;
    int slot = atomicAdd(&bincnt[(x * nb + b) * CSTRIDE], 1);
    if (slot < RCAP) {
        uint2 rec;
        rec.x = (unsigned int)r;
        rec.y = ((unsigned int)(c & (BND - 1)) << 15) | w15;
        bins[((size_t)(x * nb + b)) * RCAP + slot] = rec;
    } else {
        int si = atomicAdd(spill_cnt, 1);
        spill[si] = make_uint2((unsigned int)r, ((unsigned int)c << 15) | w15);
    }
}

// Phase B: one block per bucket. Assemble 256 ELL rows + deg + cnt in LDS,
// then burst-write contiguous 16KB. All random scatter stays on-chip.
__global__ void __launch_bounds__(256)
k_build(const uint2* __restrict__ bins, const int* __restrict__ bincnt,
        unsigned int* __restrict__ ell, float* __restrict__ deg,
        int* __restrict__ cnt, int2* __restrict__ ovf, int* __restrict__ ovf_cnt,
        int n, int nb) {
    int b = blockIdx.x;
    int c0 = b << 8;
    int nn = n - c0; if (nn > BND) nn = BND;
    __shared__ unsigned int tile[BND * CAP];   // 16 KB
    __shared__ float sdeg[BND];
    __shared__ int scnt[BND];
    int tid = threadIdx.x;
    sdeg[tid] = 0.0f; scnt[tid] = 0;
    for (int i = tid; i < BND * CAP; i += 256) tile[i] = 0u;
    __syncthreads();
    for (int x = 0; x < 8; ++x) {
        int len = bincnt[(x * nb + b) * CSTRIDE];
        if (len > RCAP) len = RCAP;
        const uint2* base = bins + ((size_t)(x * nb + b)) * RCAP;
        for (int i = tid; i < len; i += 256) {
            uint2 rec = base[i];
            int cl = (int)((rec.y >> 15) & (BND - 1));
            unsigned int w15 = rec.y & 0x7FFFu;
            atomicAdd(&sdeg[cl], f15dec(w15));
            int slot = atomicAdd(&scnt[cl], 1);
            unsigned int p = (rec.x << 15) | w15;
            if (slot < CAP) {
                tile[cl * CAP + slot] = p;
            } else {
                int oi = atomicAdd(ovf_cnt, 1);
                ovf[oi] = make_int2(c0 + cl, (int)p);
            }
        }
    }
    __syncthreads();
    for (int i = tid; i < nn * CAP; i += 256)
        ell[(size_t)c0 * CAP + i] = tile[i];
    if (tid < nn) {
        deg[c0 + tid] = sdeg[tid] + 1.0f;   // + self-loop
        cnt[c0 + tid] = scnt[tid];
    }
}

// Region-overflow replay (expected ~0 entries). Random atomics, slow path.
__global__ void k_spill(const uint2* __restrict__ spill, const int* __restrict__ spill_cnt,
                        float* __restrict__ deg, int* __restrict__ cnt,
                        unsigned int* __restrict__ ell, int2* __restrict__ ovf,
                        int* __restrict__ ovf_cnt) {
    int ns = *spill_cnt;
    int i = blockIdx.x * blockDim.x + threadIdx.x;
    int stride = gridDim.x * blockDim.x;
    for (; i < ns; i += stride) {
        uint2 rec = spill[i];
        int c = (int)(rec.y >> 15);
        unsigned int w15 = rec.y & 0x7FFFu;
        atomicAdd(&deg[c], f15dec(w15));
        int slot = atomicAdd(&cnt[c], 1);
        unsigned int p = (rec.x << 15) | w15;
        if (slot < CAP) {
            ell[(size_t)c * CAP + slot] = p;
        } else {
            int oi = atomicAdd(ovf_cnt, 1);
            ovf[oi] = make_int2(c, (int)p);
        }
    }
}

// fused: deg -> dinv (rsqrt), and segment bounds from sorted segment_ids
__global__ void k_node(float* __restrict__ deg, const int* __restrict__ seg,
                       int* __restrict__ gstart, int* __restrict__ gend, int n) {
    int i = blockIdx.x * blockDim.x + threadIdx.x;
    if (i >= n) return;
    deg[i] = rsqrtf(deg[i]);   // deg >= 1 always
    int s = seg[i];
    if (i == 0 || seg[i - 1] != s) gstart[s] = i;
    if (i == n - 1 || seg[i + 1] != s) gend[s] = i + 1;
}

// Zero aggf rows referenced by overflow entries (redundant zeroes benign).
__global__ void k_ovf_zero(const int2* __restrict__ ovf, const int* __restrict__ ovf_cnt,
                           float* __restrict__ aggf) {
    int nov = *ovf_cnt;
    int wid = (int)((blockIdx.x * (size_t)blockDim.x + threadIdx.x) >> 6);
    int lane = threadIdx.x & 63;
    int nw = (int)((gridDim.x * (size_t)blockDim.x) >> 6);
    for (int i = wid; i < nov; i += nw) {
        aggf[(size_t)ovf[i].x * NIN + lane] = 0.0f;
    }
}

// Replay node-degree-overflow edges (slot >= CAP, ~hundreds) into f32 aggf.
__global__ void k_ovf(const int2* __restrict__ ovf, const int* __restrict__ ovf_cnt,
                      const float* __restrict__ dinv, const ushort* __restrict__ x16,
                      float* __restrict__ aggf) {
    int nov = *ovf_cnt;
    int wid = (int)((blockIdx.x * (size_t)blockDim.x + threadIdx.x) >> 6);
    int lane = threadIdx.x & 63;
    int nw = (int)((gridDim.x * (size_t)blockDim.x) >> 6);
    for (int i = wid; i < nov; i += nw) {
        int2 ov = ovf[i];
        int c = ov.x;
        unsigned int p = (unsigned int)ov.y;
        int r = (int)(p >> 15);
        float w = f15dec(p & 0x7FFFu) * dinv[r] * dinv[c];
        atomicAdd(&aggf[(size_t)c * NIN + lane], w * bf2f(x16[(size_t)r * NIN + lane]));
    }
}

// Quarter-wave gather: 4 nodes/wave, 16 lanes/node, ushort4 per lane.
__global__ void __launch_bounds__(256)
k_gather(const ushort* __restrict__ x16, const float* __restrict__ dinv,
         const int* __restrict__ cnt, const unsigned int* __restrict__ ell,
         const float* __restrict__ aggf, ushort* __restrict__ agg16,
         const float* __restrict__ Wp, const float* __restrict__ bp,
         float* __restrict__ score, int n) {
    int wid = (int)((blockIdx.x * (size_t)blockDim.x + threadIdx.x) >> 6);
    int lane = threadIdx.x & 63;
    int q = lane >> 4, l = lane & 15;
    int c0 = wid * 4;
    if (c0 >= n) return;
    int c = c0 + q;
    bool valid = c < n;
    int cc = valid ? c : (n - 1);

    int cr = cnt[cc];
    int m = valid ? (cr < CAP ? cr : CAP) : 0;
    float di = dinv[cc];

    // lane l holds slot l of its node's ELL row (wave: 4 nodes x 64B contiguous)
    unsigned int pe = ell[(size_t)cc * CAP + l];
    int pr = (int)(pe >> 15);
    float pw = f15dec(pe & 0x7FFFu) * dinv[pr];   // w' = dinv[r]*ew

    const ushort4* xv4 = (const ushort4*)x16;
    ushort4 xs = xv4[(size_t)cc * 16 + l];
    float a0 = di * bf2f(xs.x), a1 = di * bf2f(xs.y);
    float a2 = di * bf2f(xs.z), a3 = di * bf2f(xs.w);

    int base = lane & 48;   // first lane of this quarter
    #pragma unroll
    for (int k = 0; k < 8; ++k) {
        int rk = __shfl(pr, base + k);
        float wk = __shfl(pw, base + k);
        bool v = k < m;
        int r = v ? rk : 0;
        float w = v ? wk : 0.0f;
        ushort4 xr = xv4[(size_t)r * 16 + l];
        a0 = fmaf(w, bf2f(xr.x), a0);
        a1 = fmaf(w, bf2f(xr.y), a1);
        a2 = fmaf(w, bf2f(xr.z), a2);
        a3 = fmaf(w, bf2f(xr.w), a3);
    }
    if (__any(m > 8)) {
        #pragma unroll
        for (int k = 8; k < CAP; ++k) {
            int rk = __shfl(pr, base + k);
            float wk = __shfl(pw, base + k);
            bool v = k < m;
            int r = v ? rk : 0;
            float w = v ? wk : 0.0f;
            ushort4 xr = xv4[(size_t)r * 16 + l];
            a0 = fmaf(w, bf2f(xr.x), a0);
            a1 = fmaf(w, bf2f(xr.y), a1);
            a2 = fmaf(w, bf2f(xr.z), a2);
            a3 = fmaf(w, bf2f(xr.w), a3);
        }
    }
    a0 *= di; a1 *= di; a2 *= di; a3 *= di;

    if (valid && cr > CAP) {
        const float4* af4 = (const float4*)aggf;
        float4 fo = af4[(size_t)cc * 16 + l];
        a0 += fo.x; a1 += fo.y; a2 += fo.z; a3 += fo.w;
    }

    if (valid) {
        ushort4 ho;
        ho.x = f2bf(a0); ho.y = f2bf(a1); ho.z = f2bf(a2); ho.w = f2bf(a3);
        ((ushort4*)agg16)[(size_t)cc * 16 + l] = ho;
    }

    const float4* wp4 = (const float4*)Wp;
    float4 wv = wp4[l];
    float part = a0 * wv.x + a1 * wv.y + a2 * wv.z + a3 * wv.w;
    part += __shfl_xor(part, 1);
    part += __shfl_xor(part, 2);
    part += __shfl_xor(part, 4);
    part += __shfl_xor(part, 8);
    if (l == 0 && valid) score[c] = part + bp[0];
}

// POOL_SPLIT blocks per graph. Fused per-graph softmax; W column in 16 NAMED
// float4s; node agg row staged via LDS broadcast; 4 FMA chains; prefetch.
#define WLOAD(i) float4 wq##i = make_float4(We[(4*(i)+0)*NIN+lane], We[(4*(i)+1)*NIN+lane], \
                                            We[(4*(i)+2)*NIN+lane], We[(4*(i)+3)*NIN+lane]);
#define WSTEP(i) { float4 av = *(const float4*)&als[wv][4*(i)]; \
    e0 = fmaf(av.x, wq##i.x, e0); e1 = fmaf(av.y, wq##i.y, e1); \
    e2 = fmaf(av.z, wq##i.z, e2); e3 = fmaf(av.w, wq##i.w, e3); }

__global__ void __launch_bounds__(256)
k_pool(const ushort* __restrict__ agg16, const float* __restrict__ score,
       const float* __restrict__ We, const float* __restrict__ be,
       const int* __restrict__ gstart, const int* __restrict__ gend,
       float* __restrict__ out) {
    int g = blockIdx.x / POOL_SPLIT;
    int p = blockIdx.x % POOL_SPLIT;
    int tid = threadIdx.x;
    int wv = tid >> 6, lane = tid & 63;
    int s = gstart[g], e = gend[g];

    __shared__ float red[4];
    __shared__ float bc;

    float mx = -3.402823466e38f;
    for (int i = s + tid; i < e; i += 256) mx = fmaxf(mx, score[i]);
    #pragma unroll
    for (int off = 32; off > 0; off >>= 1) mx = fmaxf(mx, __shfl_xor(mx, off));
    if (lane == 0) red[wv] = mx;
    __syncthreads();
    if (tid == 0) bc = fmaxf(fmaxf(red[0], red[1]), fmaxf(red[2], red[3]));
    __syncthreads();
    float m = bc;
    __syncthreads();

    float sm = 0.0f;
    for (int i = s + tid; i < e; i += 256) sm += __expf(score[i] - m);
    sm = wave_reduce_sum(sm);
    if (lane == 0) red[wv] = sm;
    __syncthreads();
    if (tid == 0) bc = red[0] + red[1] + red[2] + red[3];
    __syncthreads();
    float invz = (bc > 0.0f) ? 1.0f / bc : 0.0f;

    WLOAD(0) WLOAD(1) WLOAD(2) WLOAD(3) WLOAD(4) WLOAD(5) WLOAD(6) WLOAD(7)
    WLOAD(8) WLOAD(9) WLOAD(10) WLOAD(11) WLOAD(12) WLOAD(13) WLOAD(14) WLOAD(15)
    float bj = be[lane];

    __shared__ float als[4][NIN];
    __shared__ float part[4][NIN];

    const int stride = POOL_SPLIT * 4;
    int n = s + p * 4 + wv;
    float acc = 0.0f;

    float a_cur = 0.0f, sw_cur = 0.0f;
    if (n < e) {
        a_cur = bf2f(agg16[(size_t)n * NIN + lane]);
        sw_cur = __expf(score[n] - m) * invz;
    }
    while (n < e) {
        int nn = n + stride;
        bool vn = nn < e;
        int ni = vn ? nn : n;
        float a_nxt = bf2f(agg16[(size_t)ni * NIN + lane]);   // prefetch
        float sw_nxt = __expf(score[ni] - m) * invz;

        als[wv][lane] = a_cur;
        float e0 = bj, e1 = 0.0f, e2 = 0.0f, e3 = 0.0f;
        WSTEP(0) WSTEP(1) WSTEP(2) WSTEP(3) WSTEP(4) WSTEP(5) WSTEP(6) WSTEP(7)
        WSTEP(8) WSTEP(9) WSTEP(10) WSTEP(11) WSTEP(12) WSTEP(13) WSTEP(14) WSTEP(15)
        float emb = fmaxf(e0 + e1 + e2 + e3, 0.0f);
        acc = fmaf(sw_cur, emb, acc);

        a_cur = a_nxt; sw_cur = sw_nxt;
        n = nn;
    }
    part[wv][lane] = acc;
    __syncthreads();
    if (wv == 0) {
        float r = part[0][lane] + part[1][lane] + part[2][lane] + part[3][lane];
        atomicAdd(&out[(size_t)g * NIN + lane], r);
    }
}

extern "C" void kernel_launch(void* const* d_in, const int* in_sizes, int n_in,
                              void* d_out, int out_size, void* d_ws, size_t ws_size,
                              hipStream_t stream) {
    const float* x  = (const float*)d_in[0];
    const float* We = (const float*)d_in[1];
    const float* be = (const float*)d_in[2];
    const float* Wp = (const float*)d_in[3];
    const float* bp = (const float*)d_in[4];
    const float* ew = (const float*)d_in[5];
    const int* eidx = (const int*)d_in[6];
    const int* seg  = (const int*)d_in[7];

    int N = in_sizes[0] / NIN;
    int E = in_sizes[5];
    const int* row = eidx;
    const int* col = eidx + E;
    int nb = (N + BND - 1) / BND;

    char* w = (char*)d_ws;
    auto alloc = [&](size_t bytes) {
        char* p = w;
        w += (bytes + 255) & ~(size_t)255;
        return p;
    };
    float*          aggf      = (float*)alloc((size_t)N * NIN * sizeof(float));
    unsigned short* x16       = (unsigned short*)alloc((size_t)N * NIN * sizeof(short));
    unsigned short* agg16     = (unsigned short*)alloc((size_t)N * NIN * sizeof(short));
    float*          deg       = (float*)alloc((size_t)N * sizeof(float));
    int*            cnt       = (int*)  alloc((size_t)N * sizeof(int));
    unsigned int*   ell       = (unsigned int*)alloc((size_t)N * CAP * sizeof(unsigned int));
    uint2*          bins      = (uint2*)alloc((size_t)8 * nb * RCAP * sizeof(uint2));
    int*            bincnt    = (int*)  alloc((size_t)8 * nb * CSTRIDE * sizeof(int));
    uint2*          spill     = (uint2*)alloc((size_t)(E / 2) * sizeof(uint2));
    int*            spill_cnt = (int*)  alloc(256);
    int2*           ovf       = (int2*) alloc((size_t)(E / 2) * sizeof(int2));
    int*            ovf_cnt   = (int*)  alloc(256);
    float*          score     = (float*)alloc((size_t)N * sizeof(float));
    int*            gstart    = (int*)  alloc(GSEG * sizeof(int));
    int*            gend      = (int*)  alloc(GSEG * sizeof(int));
    float* out = (float*)d_out;

    int b = 256;
    int g_init   = (N * (NIN / 4) + b - 1) / b;
    int g_bin    = (E + b - 1) / b;
    int g_nodes  = (N + b - 1) / b;
    int nwaves   = (N + 3) / 4;
    int g_gather = (nwaves + 3) / 4;

    k_init<<<g_init, b, 0, stream>>>((ushort4*)x16, (const float4*)x, out, gstart,
                                     gend, bincnt, spill_cnt, ovf_cnt, N, nb);
    k_bin<<<g_bin, b, 0, stream>>>(row, col, ew, bincnt, bins, spill, spill_cnt, E, nb);
    k_build<<<nb, b, 0, stream>>>(bins, bincnt, ell, deg, cnt, ovf, ovf_cnt, N, nb);
    k_spill<<<16, b, 0, stream>>>(spill, spill_cnt, deg, cnt, ell, ovf, ovf_cnt);
    k_node<<<g_nodes, b, 0, stream>>>(deg, seg, gstart, gend, N);
    k_ovf_zero<<<64, b, 0, stream>>>(ovf, ovf_cnt, aggf);
    k_ovf<<<64, b, 0, stream>>>(ovf, ovf_cnt, deg, x16, aggf);
    k_gather<<<g_gather, b, 0, stream>>>(x16, deg, cnt, ell, aggf, agg16, Wp, bp, score, N);
    k_pool<<<GSEG * POOL_SPLIT, b, 0, stream>>>(agg16, score, We, be, gstart, gend, out);
}

// Round 9
// 101.423 us; speedup vs baseline: 2.4112x; 1.2117x over previous
//
#include <hip/hip_runtime.h>
#include <math.h>

#define NIN 64
#define CAP 16
#define GSEG 250
#define POOL_SPLIT 16
#define BND 256            // nodes per bucket
#define CHUNK 4096         // edges per hist/scatter block
#define NBMAX 512          // max buckets supported by LDS arrays

__device__ __forceinline__ float wave_reduce_sum(float v) {
    #pragma unroll
    for (int off = 32; off > 0; off >>= 1) v += __shfl_xor(v, off);
    return v;
}

__device__ __forceinline__ unsigned short f2bf(float f) {
    unsigned int u = __float_as_uint(f);
    u += 0x7FFFu + ((u >> 16) & 1u);   // round-to-nearest-even
    return (unsigned short)(u >> 16);
}
__device__ __forceinline__ float bf2f(unsigned short h) {
    return __uint_as_float(((unsigned int)h) << 16);
}

// 15-bit float for w in (0,1]: 5-bit exp, 10-bit mantissa.
__device__ __forceinline__ unsigned int f15enc(float w) {
    unsigned int u = __float_as_uint(w);           // w >= 0
    u += 0x0FFFu + ((u >> 13) & 1u);               // RNE to 10-bit mantissa
    int e5 = (int)(u >> 23) - 96;
    if (e5 <= 0) return 0u;                        // underflow -> 0
    unsigned int m = (u >> 13) & 0x3FFu;
    if (e5 > 31) { e5 = 31; m = 0x3FFu; }
    return ((unsigned int)e5 << 10) | m;
}
__device__ __forceinline__ float f15dec(unsigned int f) {
    if (f == 0u) return 0.0f;
    return __uint_as_float((((f >> 10) + 96u) << 23) | ((f & 0x3FFu) << 13));
}

// exclusive prefix of x across the 64-lane wave
__device__ __forceinline__ int wave_excl_scan_int(int x, int lane) {
    int inc = x;
    #pragma unroll
    for (int off = 1; off < 64; off <<= 1) {
        int y = __shfl_up(inc, off);
        if (lane >= off) inc += y;
    }
    return inc - x;
}

// init: x16 = bf16(x), out = 0, bounds zeroed (k_hist fills them), ovf_cnt = 0
__global__ void k_init(ushort4* __restrict__ x164, const float4* __restrict__ x4,
                       float* __restrict__ out, int* __restrict__ gstart,
                       int* __restrict__ gend, int* __restrict__ ovf_cnt, int n) {
    int i = blockIdx.x * blockDim.x + threadIdx.x;
    int tot = n * (NIN / 4);
    if (i < tot) {
        float4 v = x4[i];
        ushort4 h;
        h.x = f2bf(v.x); h.y = f2bf(v.y); h.z = f2bf(v.z); h.w = f2bf(v.w);
        x164[i] = h;
    }
    if (i < GSEG * NIN) out[i] = 0.0f;
    if (i < GSEG) { gstart[i] = 0; gend[i] = 0; }
    if (i == 0) *ovf_cnt = 0;
}

// Pass 1 of counting sort: per-chunk LDS histogram -> contiguous block-major row.
// Also computes segment bounds (grid-stride; after k_init's zeroing).
__global__ void __launch_bounds__(256)
k_hist(const int* __restrict__ col, int* __restrict__ ghist,
       const int* __restrict__ seg, int* __restrict__ gstart,
       int* __restrict__ gend, int e, int nb, int n) {
    __shared__ int h[NBMAX];
    int tid = threadIdx.x;
    for (int i = tid; i < NBMAX; i += 256) h[i] = 0;
    __syncthreads();
    int base = blockIdx.x * CHUNK;
    int end = base + CHUNK; if (end > e) end = e;
    for (int i = base + tid; i < end; i += 256) atomicAdd(&h[col[i] >> 8], 1);
    __syncthreads();
    for (int b = tid; b < nb; b += 256) ghist[blockIdx.x * nb + b] = h[b];

    int gsz = gridDim.x * 256;
    for (int i = blockIdx.x * 256 + tid; i < n; i += gsz) {
        int s = seg[i];
        if (i == 0 || seg[i - 1] != s) gstart[s] = i;
        if (i == n - 1 || seg[i + 1] != s) gend[s] = i + 1;
    }
}

// Pass 2a: per-bucket exclusive scan across blocks (in place), total -> btot.
__global__ void k_scanA(int* __restrict__ ghist, int* __restrict__ btot,
                        int nblk, int nb) {
    int b = blockIdx.x, lane = threadIdx.x;
    int v[4];
    #pragma unroll
    for (int j = 0; j < 4; ++j) {
        int idx = lane * 4 + j;
        v[j] = (idx < nblk) ? ghist[idx * nb + b] : 0;
    }
    int loc = v[0] + v[1] + v[2] + v[3];
    int ex = wave_excl_scan_int(loc, lane);
    int run = ex;
    #pragma unroll
    for (int j = 0; j < 4; ++j) {
        int idx = lane * 4 + j;
        if (idx < nblk) { int t = v[j]; ghist[idx * nb + b] = run; run += t; }
    }
    if (lane == 63) btot[b] = ex + loc;
}

// Pass 2b: exclusive scan of bucket totals -> bucket bases.
__global__ void k_scanB(const int* __restrict__ btot, int* __restrict__ bbase, int nb) {
    int lane = threadIdx.x;
    int v[8];
    #pragma unroll
    for (int j = 0; j < 8; ++j) {
        int idx = lane * 8 + j;
        v[j] = (idx < nb) ? btot[idx] : 0;
    }
    int loc = 0;
    #pragma unroll
    for (int j = 0; j < 8; ++j) loc += v[j];
    int ex = wave_excl_scan_int(loc, lane);
    int run = ex;
    #pragma unroll
    for (int j = 0; j < 8; ++j) {
        int idx = lane * 8 + j;
        if (idx < nb) { bbase[idx] = run; run += v[j]; }
    }
}

// Pass 3: scatter. Chunk sorted by bucket in LDS, then copied out as
// per-bucket contiguous runs (~10 recs = 84B) to the bucket-sorted bins.
// Zero global atomics; destinations fully determined by the scans.
__global__ void __launch_bounds__(256)
k_scatter(const int* __restrict__ row, const int* __restrict__ col,
          const float* __restrict__ ew, const int* __restrict__ ghist,
          const int* __restrict__ bbase, uint2* __restrict__ bins,
          int e, int nb) {
    __shared__ int h[NBMAX];
    __shared__ int loff[NBMAX];
    __shared__ int gdst[NBMAX];
    __shared__ uint2 recs[CHUNK];
    __shared__ unsigned short rb[CHUNK];
    int tid = threadIdx.x, blk = blockIdx.x;
    int base = blk * CHUNK;
    int end = base + CHUNK; if (end > e) end = e;
    int cnt = end - base;

    for (int i = tid; i < NBMAX; i += 256) h[i] = 0;
    __syncthreads();
    for (int i = base + tid; i < end; i += 256) atomicAdd(&h[col[i] >> 8], 1);
    __syncthreads();
    // wave0: exclusive scan h -> loff (local offsets within chunk)
    if (tid < 64) {
        int v[8];
        #pragma unroll
        for (int j = 0; j < 8; ++j) {
            int idx = tid * 8 + j;
            v[j] = (idx < nb) ? h[idx] : 0;
        }
        int loc = 0;
        #pragma unroll
        for (int j = 0; j < 8; ++j) loc += v[j];
        int ex = wave_excl_scan_int(loc, tid);
        int run = ex;
        #pragma unroll
        for (int j = 0; j < 8; ++j) {
            int idx = tid * 8 + j;
            if (idx < nb) { loff[idx] = run; run += v[j]; }
        }
    }
    __syncthreads();
    for (int b = tid; b < nb; b += 256) gdst[b] = bbase[b] + ghist[blk * nb + b];
    for (int i = tid; i < NBMAX; i += 256) h[i] = 0;
    __syncthreads();
    // place records into LDS, sorted by bucket
    for (int i = base + tid; i < end; i += 256) {
        int c = col[i];
        int b = c >> 8;
        uint2 rec;
        rec.x = (unsigned int)row[i];
        rec.y = ((unsigned int)(c & (BND - 1)) << 15) | f15enc(ew[i]);
        int k = atomicAdd(&h[b], 1);
        int idx = loff[b] + k;
        recs[idx] = rec;
        rb[idx] = (unsigned short)b;
    }
    __syncthreads();
    // coalesced copy-out: consecutive i in a bucket -> consecutive dests
    for (int i = tid; i < cnt; i += 256) {
        int b = rb[i];
        bins[(size_t)gdst[b] + (i - loff[b])] = recs[i];
    }
}

// Phase B: one block per bucket, reads its CONTIGUOUS record range, assembles
// ELL + deg(raw) + cnt in LDS, burst-writes. deg left raw (rsqrt inlined later).
__global__ void __launch_bounds__(256)
k_build(const uint2* __restrict__ bins, const int* __restrict__ bbase,
        const int* __restrict__ btot, unsigned int* __restrict__ ell,
        float* __restrict__ deg, int* __restrict__ cnt, int2* __restrict__ ovf,
        int* __restrict__ ovf_cnt, int n) {
    int b = blockIdx.x;
    int c0 = b << 8;
    int nn = n - c0; if (nn > BND) nn = BND;
    __shared__ unsigned int tile[BND * CAP];   // 16 KB
    __shared__ float sdeg[BND];
    __shared__ int scnt[BND];
    int tid = threadIdx.x;
    sdeg[tid] = 0.0f; scnt[tid] = 0;
    for (int i = tid; i < BND * CAP; i += 256) tile[i] = 0u;
    __syncthreads();
    int s0 = bbase[b], tot = btot[b];
    for (int i = tid; i < tot; i += 256) {
        uint2 rec = bins[(size_t)s0 + i];
        int cl = (int)((rec.y >> 15) & (BND - 1));
        unsigned int w15 = rec.y & 0x7FFFu;
        atomicAdd(&sdeg[cl], f15dec(w15));
        int slot = atomicAdd(&scnt[cl], 1);
        unsigned int p = (rec.x << 15) | w15;
        if (slot < CAP) {
            tile[cl * CAP + slot] = p;
        } else {
            int oi = atomicAdd(ovf_cnt, 1);
            ovf[oi] = make_int2(c0 + cl, (int)p);
        }
    }
    __syncthreads();
    for (int i = tid; i < nn * CAP; i += 256)
        ell[(size_t)c0 * CAP + i] = tile[i];
    if (tid < nn) {
        deg[c0 + tid] = sdeg[tid] + 1.0f;   // raw degree incl. self-loop
        cnt[c0 + tid] = scnt[tid];
    }
}

// Zero aggf rows referenced by overflow entries (redundant zeroes benign).
__global__ void k_ovf_zero(const int2* __restrict__ ovf, const int* __restrict__ ovf_cnt,
                           float* __restrict__ aggf) {
    int nov = *ovf_cnt;
    int wid = (int)((blockIdx.x * (size_t)blockDim.x + threadIdx.x) >> 6);
    int lane = threadIdx.x & 63;
    int nw = (int)((gridDim.x * (size_t)blockDim.x) >> 6);
    for (int i = wid; i < nov; i += nw) {
        aggf[(size_t)ovf[i].x * NIN + lane] = 0.0f;
    }
}

// Replay node-degree-overflow edges (slot >= CAP, ~hundreds) into f32 aggf.
__global__ void k_ovf(const int2* __restrict__ ovf, const int* __restrict__ ovf_cnt,
                      const float* __restrict__ deg, const ushort* __restrict__ x16,
                      float* __restrict__ aggf) {
    int nov = *ovf_cnt;
    int wid = (int)((blockIdx.x * (size_t)blockDim.x + threadIdx.x) >> 6);
    int lane = threadIdx.x & 63;
    int nw = (int)((gridDim.x * (size_t)blockDim.x) >> 6);
    for (int i = wid; i < nov; i += nw) {
        int2 ov = ovf[i];
        int c = ov.x;
        unsigned int p = (unsigned int)ov.y;
        int r = (int)(p >> 15);
        float w = f15dec(p & 0x7FFFu) * rsqrtf(deg[r]) * rsqrtf(deg[c]);
        atomicAdd(&aggf[(size_t)c * NIN + lane], w * bf2f(x16[(size_t)r * NIN + lane]));
    }
}

// Quarter-wave gather: 4 nodes/wave, 16 lanes/node, ushort4 per lane.
// rsqrt computed inline from raw deg (removes the k_node pass dependency).
__global__ void __launch_bounds__(256)
k_gather(const ushort* __restrict__ x16, const float* __restrict__ deg,
         const int* __restrict__ cnt, const unsigned int* __restrict__ ell,
         const float* __restrict__ aggf, ushort* __restrict__ agg16,
         const float* __restrict__ Wp, const float* __restrict__ bp,
         float* __restrict__ score, int n) {
    int wid = (int)((blockIdx.x * (size_t)blockDim.x + threadIdx.x) >> 6);
    int lane = threadIdx.x & 63;
    int q = lane >> 4, l = lane & 15;
    int c0 = wid * 4;
    if (c0 >= n) return;
    int c = c0 + q;
    bool valid = c < n;
    int cc = valid ? c : (n - 1);

    int cr = cnt[cc];
    int m = valid ? (cr < CAP ? cr : CAP) : 0;
    float di = rsqrtf(deg[cc]);

    // lane l holds slot l of its node's ELL row (wave: 4 nodes x 64B contiguous)
    unsigned int pe = ell[(size_t)cc * CAP + l];
    int pr = (int)(pe >> 15);
    float pw = f15dec(pe & 0x7FFFu) * rsqrtf(deg[pr]);   // w' = dinv[r]*ew

    const ushort4* xv4 = (const ushort4*)x16;
    ushort4 xs = xv4[(size_t)cc * 16 + l];
    float a0 = di * bf2f(xs.x), a1 = di * bf2f(xs.y);
    float a2 = di * bf2f(xs.z), a3 = di * bf2f(xs.w);

    int base = lane & 48;   // first lane of this quarter
    #pragma unroll
    for (int k = 0; k < 8; ++k) {
        int rk = __shfl(pr, base + k);
        float wk = __shfl(pw, base + k);
        bool v = k < m;
        int r = v ? rk : 0;
        float w = v ? wk : 0.0f;
        ushort4 xr = xv4[(size_t)r * 16 + l];
        a0 = fmaf(w, bf2f(xr.x), a0);
        a1 = fmaf(w, bf2f(xr.y), a1);
        a2 = fmaf(w, bf2f(xr.z), a2);
        a3 = fmaf(w, bf2f(xr.w), a3);
    }
    if (__any(m > 8)) {
        #pragma unroll
        for (int k = 8; k < CAP; ++k) {
            int rk = __shfl(pr, base + k);
            float wk = __shfl(pw, base + k);
            bool v = k < m;
            int r = v ? rk : 0;
            float w = v ? wk : 0.0f;
            ushort4 xr = xv4[(size_t)r * 16 + l];
            a0 = fmaf(w, bf2f(xr.x), a0);
            a1 = fmaf(w, bf2f(xr.y), a1);
            a2 = fmaf(w, bf2f(xr.z), a2);
            a3 = fmaf(w, bf2f(xr.w), a3);
        }
    }
    a0 *= di; a1 *= di; a2 *= di; a3 *= di;

    if (valid && cr > CAP) {
        const float4* af4 = (const float4*)aggf;
        float4 fo = af4[(size_t)cc * 16 + l];
        a0 += fo.x; a1 += fo.y; a2 += fo.z; a3 += fo.w;
    }

    if (valid) {
        ushort4 ho;
        ho.x = f2bf(a0); ho.y = f2bf(a1); ho.z = f2bf(a2); ho.w = f2bf(a3);
        ((ushort4*)agg16)[(size_t)cc * 16 + l] = ho;
    }

    const float4* wp4 = (const float4*)Wp;
    float4 wv = wp4[l];
    float part = a0 * wv.x + a1 * wv.y + a2 * wv.z + a3 * wv.w;
    part += __shfl_xor(part, 1);
    part += __shfl_xor(part, 2);
    part += __shfl_xor(part, 4);
    part += __shfl_xor(part, 8);
    if (l == 0 && valid) score[c] = part + bp[0];
}

// POOL_SPLIT blocks per graph. Fused per-graph softmax; W column in 16 NAMED
// float4s; node agg row staged via LDS broadcast; 4 FMA chains; prefetch.
#define WLOAD(i) float4 wq##i = make_float4(We[(4*(i)+0)*NIN+lane], We[(4*(i)+1)*NIN+lane], \
                                            We[(4*(i)+2)*NIN+lane], We[(4*(i)+3)*NIN+lane]);
#define WSTEP(i) { float4 av = *(const float4*)&als[wv][4*(i)]; \
    e0 = fmaf(av.x, wq##i.x, e0); e1 = fmaf(av.y, wq##i.y, e1); \
    e2 = fmaf(av.z, wq##i.z, e2); e3 = fmaf(av.w, wq##i.w, e3); }

__global__ void __launch_bounds__(256)
k_pool(const ushort* __restrict__ agg16, const float* __restrict__ score,
       const float* __restrict__ We, const float* __restrict__ be,
       const int* __restrict__ gstart, const int* __restrict__ gend,
       float* __restrict__ out) {
    int g = blockIdx.x / POOL_SPLIT;
    int p = blockIdx.x % POOL_SPLIT;
    int tid = threadIdx.x;
    int wv = tid >> 6, lane = tid & 63;
    int s = gstart[g], e = gend[g];

    __shared__ float red[4];
    __shared__ float bc;

    float mx = -3.402823466e38f;
    for (int i = s + tid; i < e; i += 256) mx = fmaxf(mx, score[i]);
    #pragma unroll
    for (int off = 32; off > 0; off >>= 1) mx = fmaxf(mx, __shfl_xor(mx, off));
    if (lane == 0) red[wv] = mx;
    __syncthreads();
    if (tid == 0) bc = fmaxf(fmaxf(red[0], red[1]), fmaxf(red[2], red[3]));
    __syncthreads();
    float m = bc;
    __syncthreads();

    float sm = 0.0f;
    for (int i = s + tid; i < e; i += 256) sm += __expf(score[i] - m);
    sm = wave_reduce_sum(sm);
    if (lane == 0) red[wv] = sm;
    __syncthreads();
    if (tid == 0) bc = red[0] + red[1] + red[2] + red[3];
    __syncthreads();
    float invz = (bc > 0.0f) ? 1.0f / bc : 0.0f;

    WLOAD(0) WLOAD(1) WLOAD(2) WLOAD(3) WLOAD(4) WLOAD(5) WLOAD(6) WLOAD(7)
    WLOAD(8) WLOAD(9) WLOAD(10) WLOAD(11) WLOAD(12) WLOAD(13) WLOAD(14) WLOAD(15)
    float bj = be[lane];

    __shared__ float als[4][NIN];
    __shared__ float part[4][NIN];

    const int stride = POOL_SPLIT * 4;
    int n = s + p * 4 + wv;
    float acc = 0.0f;

    float a_cur = 0.0f, sw_cur = 0.0f;
    if (n < e) {
        a_cur = bf2f(agg16[(size_t)n * NIN + lane]);
        sw_cur = __expf(score[n] - m) * invz;
    }
    while (n < e) {
        int nn = n + stride;
        bool vn = nn < e;
        int ni = vn ? nn : n;
        float a_nxt = bf2f(agg16[(size_t)ni * NIN + lane]);   // prefetch
        float sw_nxt = __expf(score[ni] - m) * invz;

        als[wv][lane] = a_cur;
        float e0 = bj, e1 = 0.0f, e2 = 0.0f, e3 = 0.0f;
        WSTEP(0) WSTEP(1) WSTEP(2) WSTEP(3) WSTEP(4) WSTEP(5) WSTEP(6) WSTEP(7)
        WSTEP(8) WSTEP(9) WSTEP(10) WSTEP(11) WSTEP(12) WSTEP(13) WSTEP(14) WSTEP(15)
        float emb = fmaxf(e0 + e1 + e2 + e3, 0.0f);
        acc = fmaf(sw_cur, emb, acc);

        a_cur = a_nxt; sw_cur = sw_nxt;
        n = nn;
    }
    part[wv][lane] = acc;
    __syncthreads();
    if (wv == 0) {
        float r = part[0][lane] + part[1][lane] + part[2][lane] + part[3][lane];
        atomicAdd(&out[(size_t)g * NIN + lane], r);
    }
}

extern "C" void kernel_launch(void* const* d_in, const int* in_sizes, int n_in,
                              void* d_out, int out_size, void* d_ws, size_t ws_size,
                              hipStream_t stream) {
    const float* x  = (const float*)d_in[0];
    const float* We = (const float*)d_in[1];
    const float* be = (const float*)d_in[2];
    const float* Wp = (const float*)d_in[3];
    const float* bp = (const float*)d_in[4];
    const float* ew = (const float*)d_in[5];
    const int* eidx = (const int*)d_in[6];
    const int* seg  = (const int*)d_in[7];

    int N = in_sizes[0] / NIN;
    int E = in_sizes[5];
    const int* row = eidx;
    const int* col = eidx + E;
    int nb   = (N + BND - 1) / BND;       // 391
    int nblk = (E + CHUNK - 1) / CHUNK;   // 196

    char* w = (char*)d_ws;
    auto alloc = [&](size_t bytes) {
        char* p = w;
        w += (bytes + 255) & ~(size_t)255;
        return p;
    };
    float*          aggf    = (float*)alloc((size_t)N * NIN * sizeof(float));
    unsigned short* x16     = (unsigned short*)alloc((size_t)N * NIN * sizeof(short));
    unsigned short* agg16   = (unsigned short*)alloc((size_t)N * NIN * sizeof(short));
    float*          deg     = (float*)alloc((size_t)N * sizeof(float));
    int*            cnt     = (int*)  alloc((size_t)N * sizeof(int));
    unsigned int*   ell     = (unsigned int*)alloc((size_t)N * CAP * sizeof(unsigned int));
    uint2*          bins    = (uint2*)alloc((size_t)E * sizeof(uint2));
    int*            ghist   = (int*)  alloc((size_t)nblk * nb * sizeof(int));
    int*            btot    = (int*)  alloc((size_t)nb * sizeof(int));
    int*            bbase   = (int*)  alloc((size_t)nb * sizeof(int));
    int2*           ovf     = (int2*) alloc((size_t)(E / 4) * sizeof(int2));
    int*            ovf_cnt = (int*)  alloc(256);
    float*          score   = (float*)alloc((size_t)N * sizeof(float));
    int*            gstart  = (int*)  alloc(GSEG * sizeof(int));
    int*            gend    = (int*)  alloc(GSEG * sizeof(int));
    float* out = (float*)d_out;

    int b = 256;
    int g_init   = (N * (NIN / 4) + b - 1) / b;
    int nwaves   = (N + 3) / 4;
    int g_gather = (nwaves + 3) / 4;

    k_init<<<g_init, b, 0, stream>>>((ushort4*)x16, (const float4*)x, out, gstart,
                                     gend, ovf_cnt, N);
    k_hist<<<nblk, b, 0, stream>>>(col, ghist, seg, gstart, gend, E, nb, N);
    k_scanA<<<nb, 64, 0, stream>>>(ghist, btot, nblk, nb);
    k_scanB<<<1, 64, 0, stream>>>(btot, bbase, nb);
    k_scatter<<<nblk, b, 0, stream>>>(row, col, ew, ghist, bbase, bins, E, nb);
    k_build<<<nb, b, 0, stream>>>(bins, bbase, btot, ell, deg, cnt, ovf, ovf_cnt, N);
    k_ovf_zero<<<64, b, 0, stream>>>(ovf, ovf_cnt, aggf);
    k_ovf<<<64, b, 0, stream>>>(ovf, ovf_cnt, deg, x16, aggf);
    k_gather<<<g_gather, b, 0, stream>>>(x16, deg, cnt, ell, aggf, agg16, Wp, bp, score, N);
    k_pool<<<GSEG * POOL_SPLIT, b, 0, stream>>>(agg16, score, We, be, gstart, gend, out);
}

// Round 10
// 94.017 us; speedup vs baseline: 2.6012x; 1.0788x over previous
//
#include <hip/hip_runtime.h>
#include <math.h>

#define NIN 64
#define CAP 16
#define GSEG 250
#define POOL_SPLIT 16
#define BND 256            // nodes per bucket
#define CHUNK 2048         // edges per hist/scatter block
#define NBMAX 512          // max buckets / max chunks supported by scans

__device__ __forceinline__ float wave_reduce_sum(float v) {
    #pragma unroll
    for (int off = 32; off > 0; off >>= 1) v += __shfl_xor(v, off);
    return v;
}

__device__ __forceinline__ unsigned short f2bf(float f) {
    unsigned int u = __float_as_uint(f);
    u += 0x7FFFu + ((u >> 16) & 1u);   // round-to-nearest-even
    return (unsigned short)(u >> 16);
}
__device__ __forceinline__ float bf2f(unsigned short h) {
    return __uint_as_float(((unsigned int)h) << 16);
}

// 15-bit float for w in (0,1]: 5-bit exp, 10-bit mantissa.
__device__ __forceinline__ unsigned int f15enc(float w) {
    unsigned int u = __float_as_uint(w);           // w >= 0
    u += 0x0FFFu + ((u >> 13) & 1u);               // RNE to 10-bit mantissa
    int e5 = (int)(u >> 23) - 96;
    if (e5 <= 0) return 0u;                        // underflow -> 0
    unsigned int m = (u >> 13) & 0x3FFu;
    if (e5 > 31) { e5 = 31; m = 0x3FFu; }
    return ((unsigned int)e5 << 10) | m;
}
__device__ __forceinline__ float f15dec(unsigned int f) {
    if (f == 0u) return 0.0f;
    return __uint_as_float((((f >> 10) + 96u) << 23) | ((f & 0x3FFu) << 13));
}

// exclusive prefix of x across the 64-lane wave
__device__ __forceinline__ int wave_excl_scan_int(int x, int lane) {
    int inc = x;
    #pragma unroll
    for (int off = 1; off < 64; off <<= 1) {
        int y = __shfl_up(inc, off);
        if (lane >= off) inc += y;
    }
    return inc - x;
}

// wave0 helper: exclusive scan of src[0..nb) (global) into dst (LDS).
// Call from all 256 threads; caller must __syncthreads() after.
__device__ __forceinline__ void scan512_to_lds(const int* __restrict__ src,
                                               int* __restrict__ dst,
                                               int nb, int tid) {
    if (tid < 64) {
        int v[8];
        #pragma unroll
        for (int j = 0; j < 8; ++j) {
            int idx = tid * 8 + j;
            v[j] = (idx < nb) ? src[idx] : 0;
        }
        int loc = 0;
        #pragma unroll
        for (int j = 0; j < 8; ++j) loc += v[j];
        int ex = wave_excl_scan_int(loc, tid);
        int run = ex;
        #pragma unroll
        for (int j = 0; j < 8; ++j) {
            int idx = tid * 8 + j;
            if (idx < nb) { dst[idx] = run; run += v[j]; }
        }
    }
}

// Fused prep: x16 = bf16(x); out/bounds/ovf_cnt zeroed; per-chunk LDS histogram.
__global__ void __launch_bounds__(256)
k_prep(ushort4* __restrict__ x164, const float4* __restrict__ x4,
       float* __restrict__ out, int* __restrict__ gstart, int* __restrict__ gend,
       int* __restrict__ ovf_cnt, const int* __restrict__ col,
       int* __restrict__ ghist, int n, int e, int nb, int nblk) {
    __shared__ int h[NBMAX];
    int tid = threadIdx.x, blk = blockIdx.x;
    int i = blk * 256 + tid;
    int tot = n * (NIN / 4);
    if (i < tot) {
        float4 v = x4[i];
        ushort4 hh;
        hh.x = f2bf(v.x); hh.y = f2bf(v.y); hh.z = f2bf(v.z); hh.w = f2bf(v.w);
        x164[i] = hh;
    }
    if (i < GSEG * NIN) out[i] = 0.0f;
    if (i < GSEG) { gstart[i] = 0; gend[i] = 0; }
    if (i == 0) *ovf_cnt = 0;
    if (blk < nblk) {
        for (int j = tid; j < NBMAX; j += 256) h[j] = 0;
        __syncthreads();
        int base = blk * CHUNK;
        int end = base + CHUNK; if (end > e) end = e;
        for (int j = base + tid; j < end; j += 256) atomicAdd(&h[col[j] >> 8], 1);
        __syncthreads();
        for (int b = tid; b < nb; b += 256) ghist[blk * nb + b] = h[b];
    }
}

// Per-bucket exclusive scan across chunks (in place), totals -> btot.
// Also sets segment bounds (after k_prep's zeroing).
__global__ void k_scanA(int* __restrict__ ghist, int* __restrict__ btot,
                        const int* __restrict__ seg, int* __restrict__ gstart,
                        int* __restrict__ gend, int nblk, int nb, int n) {
    int b = blockIdx.x, lane = threadIdx.x;
    int v[8];
    #pragma unroll
    for (int j = 0; j < 8; ++j) {
        int idx = lane * 8 + j;
        v[j] = (idx < nblk) ? ghist[idx * nb + b] : 0;
    }
    int loc = 0;
    #pragma unroll
    for (int j = 0; j < 8; ++j) loc += v[j];
    int ex = wave_excl_scan_int(loc, lane);
    int run = ex;
    #pragma unroll
    for (int j = 0; j < 8; ++j) {
        int idx = lane * 8 + j;
        if (idx < nblk) { int t = v[j]; ghist[idx * nb + b] = run; run += t; }
    }
    if (lane == 63) btot[b] = ex + loc;

    int gsz = gridDim.x * 64;
    for (int i = b * 64 + lane; i < n; i += gsz) {
        int s = seg[i];
        if (i == 0 || seg[i - 1] != s) gstart[s] = i;
        if (i == n - 1 || seg[i + 1] != s) gend[s] = i + 1;
    }
}

// Scatter: chunk sorted by bucket in LDS, copied out as contiguous runs.
// Bucket bases derived in-block from btot (saves the scanB launch).
__global__ void __launch_bounds__(256)
k_scatter(const int* __restrict__ row, const int* __restrict__ col,
          const float* __restrict__ ew, const int* __restrict__ ghist,
          const int* __restrict__ btot, uint2* __restrict__ bins,
          int e, int nb) {
    __shared__ int h[NBMAX];
    __shared__ int loff[NBMAX];
    __shared__ int gdst[NBMAX];
    __shared__ int bb[NBMAX];
    __shared__ uint2 recs[CHUNK];
    __shared__ unsigned short rb[CHUNK];
    int tid = threadIdx.x, blk = blockIdx.x;
    int base = blk * CHUNK;
    int end = base + CHUNK; if (end > e) end = e;
    int cnt = end - base;

    for (int i = tid; i < NBMAX; i += 256) h[i] = 0;
    __syncthreads();
    for (int i = base + tid; i < end; i += 256) atomicAdd(&h[col[i] >> 8], 1);
    __syncthreads();
    if (tid < 64) {
        int v[8];
        #pragma unroll
        for (int j = 0; j < 8; ++j) {
            int idx = tid * 8 + j;
            v[j] = (idx < nb) ? h[idx] : 0;
        }
        int loc = 0;
        #pragma unroll
        for (int j = 0; j < 8; ++j) loc += v[j];
        int ex = wave_excl_scan_int(loc, tid);
        int run = ex;
        #pragma unroll
        for (int j = 0; j < 8; ++j) {
            int idx = tid * 8 + j;
            if (idx < nb) { loff[idx] = run; run += v[j]; }
        }
    }
    scan512_to_lds(btot, bb, nb, tid);
    __syncthreads();
    for (int b = tid; b < nb; b += 256) gdst[b] = bb[b] + ghist[blk * nb + b];
    for (int i = tid; i < NBMAX; i += 256) h[i] = 0;
    __syncthreads();
    for (int i = base + tid; i < end; i += 256) {
        int c = col[i];
        int b = c >> 8;
        uint2 rec;
        rec.x = (unsigned int)row[i];
        rec.y = ((unsigned int)(c & (BND - 1)) << 15) | f15enc(ew[i]);
        int k = atomicAdd(&h[b], 1);
        int idx = loff[b] + k;
        recs[idx] = rec;
        rb[idx] = (unsigned short)b;
    }
    __syncthreads();
    for (int i = tid; i < cnt; i += 256) {
        int b = rb[i];
        bins[(size_t)gdst[b] + (i - loff[b])] = recs[i];
    }
}

// Build: one block per bucket; contiguous record range; ELL+deg+cnt in LDS,
// burst-write. Also zeroes aggf rows of ITS OWN overflowed nodes (exclusive).
__global__ void __launch_bounds__(256)
k_build(const uint2* __restrict__ bins, const int* __restrict__ btot,
        unsigned int* __restrict__ ell, float* __restrict__ deg,
        int* __restrict__ cnt, int2* __restrict__ ovf, int* __restrict__ ovf_cnt,
        float* __restrict__ aggf, int n, int nb) {
    int b = blockIdx.x;
    int c0 = b << 8;
    int nn = n - c0; if (nn > BND) nn = BND;
    __shared__ unsigned int tile[BND * CAP];   // 16 KB
    __shared__ float sdeg[BND];
    __shared__ int scnt[BND];
    __shared__ int bb[NBMAX];
    __shared__ int ovl[BND];
    __shared__ int novloc;
    int tid = threadIdx.x;
    sdeg[tid] = 0.0f; scnt[tid] = 0;
    if (tid == 0) novloc = 0;
    for (int i = tid; i < BND * CAP; i += 256) tile[i] = 0u;
    scan512_to_lds(btot, bb, nb, tid);
    __syncthreads();
    int s0 = bb[b], tot = btot[b];
    for (int i = tid; i < tot; i += 256) {
        uint2 rec = bins[(size_t)s0 + i];
        int cl = (int)((rec.y >> 15) & (BND - 1));
        unsigned int w15 = rec.y & 0x7FFFu;
        atomicAdd(&sdeg[cl], f15dec(w15));
        int slot = atomicAdd(&scnt[cl], 1);
        unsigned int p = (rec.x << 15) | w15;
        if (slot < CAP) {
            tile[cl * CAP + slot] = p;
        } else {
            int oi = atomicAdd(ovf_cnt, 1);
            ovf[oi] = make_int2(c0 + cl, (int)p);
        }
    }
    __syncthreads();
    for (int i = tid; i < nn * CAP; i += 256)
        ell[(size_t)c0 * CAP + i] = tile[i];
    if (tid < nn) {
        deg[c0 + tid] = sdeg[tid] + 1.0f;   // raw degree incl. self-loop
        cnt[c0 + tid] = scnt[tid];
        if (scnt[tid] > CAP) { int k = atomicAdd(&novloc, 1); ovl[k] = tid; }
    }
    __syncthreads();
    int nov = novloc;
    for (int k = 0; k < nov; ++k) {
        if (tid < NIN) aggf[(size_t)(c0 + ovl[k]) * NIN + tid] = 0.0f;
    }
}

// Replay node-degree-overflow edges (slot >= CAP, ~hundreds) into f32 aggf.
__global__ void k_ovf(const int2* __restrict__ ovf, const int* __restrict__ ovf_cnt,
                      const float* __restrict__ deg, const ushort* __restrict__ x16,
                      float* __restrict__ aggf) {
    int nov = *ovf_cnt;
    int wid = (int)((blockIdx.x * (size_t)blockDim.x + threadIdx.x) >> 6);
    int lane = threadIdx.x & 63;
    int nw = (int)((gridDim.x * (size_t)blockDim.x) >> 6);
    for (int i = wid; i < nov; i += nw) {
        int2 ov = ovf[i];
        int c = ov.x;
        unsigned int p = (unsigned int)ov.y;
        int r = (int)(p >> 15);
        float w = f15dec(p & 0x7FFFu) * rsqrtf(deg[r]) * rsqrtf(deg[c]);
        atomicAdd(&aggf[(size_t)c * NIN + lane], w * bf2f(x16[(size_t)r * NIN + lane]));
    }
}

// Quarter-wave gather: 4 nodes/wave, 16 lanes/node, ushort4 per lane.
__global__ void __launch_bounds__(256)
k_gather(const ushort* __restrict__ x16, const float* __restrict__ deg,
         const int* __restrict__ cnt, const unsigned int* __restrict__ ell,
         const float* __restrict__ aggf, ushort* __restrict__ agg16,
         const float* __restrict__ Wp, const float* __restrict__ bp,
         float* __restrict__ score, int n) {
    int wid = (int)((blockIdx.x * (size_t)blockDim.x + threadIdx.x) >> 6);
    int lane = threadIdx.x & 63;
    int q = lane >> 4, l = lane & 15;
    int c0 = wid * 4;
    if (c0 >= n) return;
    int c = c0 + q;
    bool valid = c < n;
    int cc = valid ? c : (n - 1);

    int cr = cnt[cc];
    int m = valid ? (cr < CAP ? cr : CAP) : 0;
    float di = rsqrtf(deg[cc]);

    unsigned int pe = ell[(size_t)cc * CAP + l];
    int pr = (int)(pe >> 15);
    float pw = f15dec(pe & 0x7FFFu) * rsqrtf(deg[pr]);   // w' = dinv[r]*ew

    const ushort4* xv4 = (const ushort4*)x16;
    ushort4 xs = xv4[(size_t)cc * 16 + l];
    float a0 = di * bf2f(xs.x), a1 = di * bf2f(xs.y);
    float a2 = di * bf2f(xs.z), a3 = di * bf2f(xs.w);

    int base = lane & 48;   // first lane of this quarter
    #pragma unroll
    for (int k = 0; k < 8; ++k) {
        int rk = __shfl(pr, base + k);
        float wk = __shfl(pw, base + k);
        bool v = k < m;
        int r = v ? rk : 0;
        float w = v ? wk : 0.0f;
        ushort4 xr = xv4[(size_t)r * 16 + l];
        a0 = fmaf(w, bf2f(xr.x), a0);
        a1 = fmaf(w, bf2f(xr.y), a1);
        a2 = fmaf(w, bf2f(xr.z), a2);
        a3 = fmaf(w, bf2f(xr.w), a3);
    }
    if (__any(m > 8)) {
        #pragma unroll
        for (int k = 8; k < CAP; ++k) {
            int rk = __shfl(pr, base + k);
            float wk = __shfl(pw, base + k);
            bool v = k < m;
            int r = v ? rk : 0;
            float w = v ? wk : 0.0f;
            ushort4 xr = xv4[(size_t)r * 16 + l];
            a0 = fmaf(w, bf2f(xr.x), a0);
            a1 = fmaf(w, bf2f(xr.y), a1);
            a2 = fmaf(w, bf2f(xr.z), a2);
            a3 = fmaf(w, bf2f(xr.w), a3);
        }
    }
    a0 *= di; a1 *= di; a2 *= di; a3 *= di;

    if (valid && cr > CAP) {
        const float4* af4 = (const float4*)aggf;
        float4 fo = af4[(size_t)cc * 16 + l];
        a0 += fo.x; a1 += fo.y; a2 += fo.z; a3 += fo.w;
    }

    if (valid) {
        ushort4 ho;
        ho.x = f2bf(a0); ho.y = f2bf(a1); ho.z = f2bf(a2); ho.w = f2bf(a3);
        ((ushort4*)agg16)[(size_t)cc * 16 + l] = ho;
    }

    const float4* wp4 = (const float4*)Wp;
    float4 wv = wp4[l];
    float part = a0 * wv.x + a1 * wv.y + a2 * wv.z + a3 * wv.w;
    part += __shfl_xor(part, 1);
    part += __shfl_xor(part, 2);
    part += __shfl_xor(part, 4);
    part += __shfl_xor(part, 8);
    if (l == 0 && valid) score[c] = part + bp[0];
}

// POOL_SPLIT blocks per graph. Fused per-graph softmax; W column in 16 NAMED
// float4s; node agg row staged via LDS broadcast; 4 FMA chains; prefetch.
#define WLOAD(i) float4 wq##i = make_float4(We[(4*(i)+0)*NIN+lane], We[(4*(i)+1)*NIN+lane], \
                                            We[(4*(i)+2)*NIN+lane], We[(4*(i)+3)*NIN+lane]);
#define WSTEP(i) { float4 av = *(const float4*)&als[wv][4*(i)]; \
    e0 = fmaf(av.x, wq##i.x, e0); e1 = fmaf(av.y, wq##i.y, e1); \
    e2 = fmaf(av.z, wq##i.z, e2); e3 = fmaf(av.w, wq##i.w, e3); }

__global__ void __launch_bounds__(256)
k_pool(const ushort* __restrict__ agg16, const float* __restrict__ score,
       const float* __restrict__ We, const float* __restrict__ be,
       const int* __restrict__ gstart, const int* __restrict__ gend,
       float* __restrict__ out) {
    int g = blockIdx.x / POOL_SPLIT;
    int p = blockIdx.x % POOL_SPLIT;
    int tid = threadIdx.x;
    int wv = tid >> 6, lane = tid & 63;
    int s = gstart[g], e = gend[g];

    __shared__ float red[4];
    __shared__ float bc;

    float mx = -3.402823466e38f;
    for (int i = s + tid; i < e; i += 256) mx = fmaxf(mx, score[i]);
    #pragma unroll
    for (int off = 32; off > 0; off >>= 1) mx = fmaxf(mx, __shfl_xor(mx, off));
    if (lane == 0) red[wv] = mx;
    __syncthreads();
    if (tid == 0) bc = fmaxf(fmaxf(red[0], red[1]), fmaxf(red[2], red[3]));
    __syncthreads();
    float m = bc;
    __syncthreads();

    float sm = 0.0f;
    for (int i = s + tid; i < e; i += 256) sm += __expf(score[i] - m);
    sm = wave_reduce_sum(sm);
    if (lane == 0) red[wv] = sm;
    __syncthreads();
    if (tid == 0) bc = red[0] + red[1] + red[2] + red[3];
    __syncthreads();
    float invz = (bc > 0.0f) ? 1.0f / bc : 0.0f;

    WLOAD(0) WLOAD(1) WLOAD(2) WLOAD(3) WLOAD(4) WLOAD(5) WLOAD(6) WLOAD(7)
    WLOAD(8) WLOAD(9) WLOAD(10) WLOAD(11) WLOAD(12) WLOAD(13) WLOAD(14) WLOAD(15)
    float bj = be[lane];

    __shared__ float als[4][NIN];
    __shared__ float part[4][NIN];

    const int stride = POOL_SPLIT * 4;
    int n = s + p * 4 + wv;
    float acc = 0.0f;

    float a_cur = 0.0f, sw_cur = 0.0f;
    if (n < e) {
        a_cur = bf2f(agg16[(size_t)n * NIN + lane]);
        sw_cur = __expf(score[n] - m) * invz;
    }
    while (n < e) {
        int nn = n + stride;
        bool vn = nn < e;
        int ni = vn ? nn : n;
        float a_nxt = bf2f(agg16[(size_t)ni * NIN + lane]);   // prefetch
        float sw_nxt = __expf(score[ni] - m) * invz;

        als[wv][lane] = a_cur;
        float e0 = bj, e1 = 0.0f, e2 = 0.0f, e3 = 0.0f;
        WSTEP(0) WSTEP(1) WSTEP(2) WSTEP(3) WSTEP(4) WSTEP(5) WSTEP(6) WSTEP(7)
        WSTEP(8) WSTEP(9) WSTEP(10) WSTEP(11) WSTEP(12) WSTEP(13) WSTEP(14) WSTEP(15)
        float emb = fmaxf(e0 + e1 + e2 + e3, 0.0f);
        acc = fmaf(sw_cur, emb, acc);

        a_cur = a_nxt; sw_cur = sw_nxt;
        n = nn;
    }
    part[wv][lane] = acc;
    __syncthreads();
    if (wv == 0) {
        float r = part[0][lane] + part[1][lane] + part[2][lane] + part[3][lane];
        atomicAdd(&out[(size_t)g * NIN + lane], r);
    }
}

extern "C" void kernel_launch(void* const* d_in, const int* in_sizes, int n_in,
                              void* d_out, int out_size, void* d_ws, size_t ws_size,
                              hipStream_t stream) {
    const float* x  = (const float*)d_in[0];
    const float* We = (const float*)d_in[1];
    const float* be = (const float*)d_in[2];
    const float* Wp = (const float*)d_in[3];
    const float* bp = (const float*)d_in[4];
    const float* ew = (const float*)d_in[5];
    const int* eidx = (const int*)d_in[6];
    const int* seg  = (const int*)d_in[7];

    int N = in_sizes[0] / NIN;
    int E = in_sizes[5];
    const int* row = eidx;
    const int* col = eidx + E;
    int nb   = (N + BND - 1) / BND;       // 391
    int nblk = (E + CHUNK - 1) / CHUNK;   // 391

    char* w = (char*)d_ws;
    auto alloc = [&](size_t bytes) {
        char* p = w;
        w += (bytes + 255) & ~(size_t)255;
        return p;
    };
    float*          aggf    = (float*)alloc((size_t)N * NIN * sizeof(float));
    unsigned short* x16     = (unsigned short*)alloc((size_t)N * NIN * sizeof(short));
    unsigned short* agg16   = (unsigned short*)alloc((size_t)N * NIN * sizeof(short));
    float*          deg     = (float*)alloc((size_t)N * sizeof(float));
    int*            cnt     = (int*)  alloc((size_t)N * sizeof(int));
    unsigned int*   ell     = (unsigned int*)alloc((size_t)N * CAP * sizeof(unsigned int));
    uint2*          bins    = (uint2*)alloc((size_t)E * sizeof(uint2));
    int*            ghist   = (int*)  alloc((size_t)nblk * nb * sizeof(int));
    int*            btot    = (int*)  alloc((size_t)nb * sizeof(int));
    int2*           ovf     = (int2*) alloc((size_t)(E / 4) * sizeof(int2));
    int*            ovf_cnt = (int*)  alloc(256);
    float*          score   = (float*)alloc((size_t)N * sizeof(float));
    int*            gstart  = (int*)  alloc(GSEG * sizeof(int));
    int*            gend    = (int*)  alloc(GSEG * sizeof(int));
    float* out = (float*)d_out;

    int b = 256;
    int g_prep   = (N * (NIN / 4) + b - 1) / b;   // 6250 >= nblk
    int nwaves   = (N + 3) / 4;
    int g_gather = (nwaves + 3) / 4;

    k_prep<<<g_prep, b, 0, stream>>>((ushort4*)x16, (const float4*)x, out, gstart,
                                     gend, ovf_cnt, col, ghist, N, E, nb, nblk);
    k_scanA<<<nb, 64, 0, stream>>>(ghist, btot, seg, gstart, gend, nblk, nb, N);
    k_scatter<<<nblk, b, 0, stream>>>(row, col, ew, ghist, btot, bins, E, nb);
    k_build<<<nb, b, 0, stream>>>(bins, btot, ell, deg, cnt, ovf, ovf_cnt, aggf, N, nb);
    k_ovf<<<64, b, 0, stream>>>(ovf, ovf_cnt, deg, x16, aggf);
    k_gather<<<g_gather, b, 0, stream>>>(x16, deg, cnt, ell, aggf, agg16, Wp, bp, score, N);
    k_pool<<<GSEG * POOL_SPLIT, b, 0, stream>>>(agg16, score, We, be, gstart, gend, out);
}

// Round 11
// 89.084 us; speedup vs baseline: 2.7452x; 1.0554x over previous
//
#include <hip/hip_runtime.h>
#include <math.h>

#define NIN 64
#define CAP 16
#define GSEG 250
#define POOL_SPLIT 8
#define BND 256            // nodes per bucket
#define CHUNK 2048         // edges per hist/scatter block
#define NBMAX 512          // max buckets / max chunks supported by scans

__device__ __forceinline__ float wave_reduce_sum(float v) {
    #pragma unroll
    for (int off = 32; off > 0; off >>= 1) v += __shfl_xor(v, off);
    return v;
}

__device__ __forceinline__ unsigned short f2bf(float f) {
    unsigned int u = __float_as_uint(f);
    u += 0x7FFFu + ((u >> 16) & 1u);   // round-to-nearest-even
    return (unsigned short)(u >> 16);
}
__device__ __forceinline__ float bf2f(unsigned short h) {
    return __uint_as_float(((unsigned int)h) << 16);
}
// unpack 2 bf16 from one uint (low = even element, high = odd element)
__device__ __forceinline__ float bflo(unsigned int u) { return __uint_as_float(u << 16); }
__device__ __forceinline__ float bfhi(unsigned int u) { return __uint_as_float(u & 0xFFFF0000u); }
__device__ __forceinline__ unsigned int pack2bf(float lo, float hi) {
    return (unsigned int)f2bf(lo) | ((unsigned int)f2bf(hi) << 16);
}

// 15-bit float for w in (0,1]: 5-bit exp, 10-bit mantissa.
__device__ __forceinline__ unsigned int f15enc(float w) {
    unsigned int u = __float_as_uint(w);           // w >= 0
    u += 0x0FFFu + ((u >> 13) & 1u);               // RNE to 10-bit mantissa
    int e5 = (int)(u >> 23) - 96;
    if (e5 <= 0) return 0u;                        // underflow -> 0
    unsigned int m = (u >> 13) & 0x3FFu;
    if (e5 > 31) { e5 = 31; m = 0x3FFu; }
    return ((unsigned int)e5 << 10) | m;
}
__device__ __forceinline__ float f15dec(unsigned int f) {
    if (f == 0u) return 0.0f;
    return __uint_as_float((((f >> 10) + 96u) << 23) | ((f & 0x3FFu) << 13));
}

// exclusive prefix of x across the 64-lane wave
__device__ __forceinline__ int wave_excl_scan_int(int x, int lane) {
    int inc = x;
    #pragma unroll
    for (int off = 1; off < 64; off <<= 1) {
        int y = __shfl_up(inc, off);
        if (lane >= off) inc += y;
    }
    return inc - x;
}

// wave0 helper: exclusive scan of src[0..nb) (global) into dst (LDS).
__device__ __forceinline__ void scan512_to_lds(const int* __restrict__ src,
                                               int* __restrict__ dst,
                                               int nb, int tid) {
    if (tid < 64) {
        int v[8];
        #pragma unroll
        for (int j = 0; j < 8; ++j) {
            int idx = tid * 8 + j;
            v[j] = (idx < nb) ? src[idx] : 0;
        }
        int loc = 0;
        #pragma unroll
        for (int j = 0; j < 8; ++j) loc += v[j];
        int ex = wave_excl_scan_int(loc, tid);
        int run = ex;
        #pragma unroll
        for (int j = 0; j < 8; ++j) {
            int idx = tid * 8 + j;
            if (idx < nb) { dst[idx] = run; run += v[j]; }
        }
    }
}

// Fused prep: x16 = bf16(x); out/bounds/ovf_cnt zeroed; per-chunk LDS histogram.
__global__ void __launch_bounds__(256)
k_prep(ushort4* __restrict__ x164, const float4* __restrict__ x4,
       float* __restrict__ out, int* __restrict__ gstart, int* __restrict__ gend,
       int* __restrict__ ovf_cnt, const int* __restrict__ col,
       int* __restrict__ ghist, int n, int e, int nb, int nblk) {
    __shared__ int h[NBMAX];
    int tid = threadIdx.x, blk = blockIdx.x;
    int i = blk * 256 + tid;
    int tot = n * (NIN / 4);
    if (i < tot) {
        float4 v = x4[i];
        ushort4 hh;
        hh.x = f2bf(v.x); hh.y = f2bf(v.y); hh.z = f2bf(v.z); hh.w = f2bf(v.w);
        x164[i] = hh;
    }
    if (i < GSEG * NIN) out[i] = 0.0f;
    if (i < GSEG) { gstart[i] = 0; gend[i] = 0; }
    if (i == 0) *ovf_cnt = 0;
    if (blk < nblk) {
        for (int j = tid; j < NBMAX; j += 256) h[j] = 0;
        __syncthreads();
        int base = blk * CHUNK;
        int end = base + CHUNK; if (end > e) end = e;
        for (int j = base + tid; j < end; j += 256) atomicAdd(&h[col[j] >> 8], 1);
        __syncthreads();
        for (int b = tid; b < nb; b += 256) ghist[blk * nb + b] = h[b];
    }
}

// Per-bucket exclusive scan across chunks (in place), totals -> btot.
// Also sets segment bounds (after k_prep's zeroing).
__global__ void k_scanA(int* __restrict__ ghist, int* __restrict__ btot,
                        const int* __restrict__ seg, int* __restrict__ gstart,
                        int* __restrict__ gend, int nblk, int nb, int n) {
    int b = blockIdx.x, lane = threadIdx.x;
    int v[8];
    #pragma unroll
    for (int j = 0; j < 8; ++j) {
        int idx = lane * 8 + j;
        v[j] = (idx < nblk) ? ghist[idx * nb + b] : 0;
    }
    int loc = 0;
    #pragma unroll
    for (int j = 0; j < 8; ++j) loc += v[j];
    int ex = wave_excl_scan_int(loc, lane);
    int run = ex;
    #pragma unroll
    for (int j = 0; j < 8; ++j) {
        int idx = lane * 8 + j;
        if (idx < nblk) { int t = v[j]; ghist[idx * nb + b] = run; run += t; }
    }
    if (lane == 63) btot[b] = ex + loc;

    int gsz = gridDim.x * 64;
    for (int i = b * 64 + lane; i < n; i += gsz) {
        int s = seg[i];
        if (i == 0 || seg[i - 1] != s) gstart[s] = i;
        if (i == n - 1 || seg[i + 1] != s) gend[s] = i + 1;
    }
}

// Scatter: chunk sorted by bucket in LDS, copied out as contiguous runs.
__global__ void __launch_bounds__(256)
k_scatter(const int* __restrict__ row, const int* __restrict__ col,
          const float* __restrict__ ew, const int* __restrict__ ghist,
          const int* __restrict__ btot, uint2* __restrict__ bins,
          int e, int nb) {
    __shared__ int h[NBMAX];
    __shared__ int loff[NBMAX];
    __shared__ int gdst[NBMAX];
    __shared__ int bb[NBMAX];
    __shared__ uint2 recs[CHUNK];
    __shared__ unsigned short rb[CHUNK];
    int tid = threadIdx.x, blk = blockIdx.x;
    int base = blk * CHUNK;
    int end = base + CHUNK; if (end > e) end = e;
    int cnt = end - base;

    for (int i = tid; i < NBMAX; i += 256) h[i] = 0;
    __syncthreads();
    for (int i = base + tid; i < end; i += 256) atomicAdd(&h[col[i] >> 8], 1);
    __syncthreads();
    if (tid < 64) {
        int v[8];
        #pragma unroll
        for (int j = 0; j < 8; ++j) {
            int idx = tid * 8 + j;
            v[j] = (idx < nb) ? h[idx] : 0;
        }
        int loc = 0;
        #pragma unroll
        for (int j = 0; j < 8; ++j) loc += v[j];
        int ex = wave_excl_scan_int(loc, tid);
        int run = ex;
        #pragma unroll
        for (int j = 0; j < 8; ++j) {
            int idx = tid * 8 + j;
            if (idx < nb) { loff[idx] = run; run += v[j]; }
        }
    }
    scan512_to_lds(btot, bb, nb, tid);
    __syncthreads();
    for (int b = tid; b < nb; b += 256) gdst[b] = bb[b] + ghist[blk * nb + b];
    for (int i = tid; i < NBMAX; i += 256) h[i] = 0;
    __syncthreads();
    for (int i = base + tid; i < end; i += 256) {
        int c = col[i];
        int b = c >> 8;
        uint2 rec;
        rec.x = (unsigned int)row[i];
        rec.y = ((unsigned int)(c & (BND - 1)) << 15) | f15enc(ew[i]);
        int k = atomicAdd(&h[b], 1);
        int idx = loff[b] + k;
        recs[idx] = rec;
        rb[idx] = (unsigned short)b;
    }
    __syncthreads();
    for (int i = tid; i < cnt; i += 256) {
        int b = rb[i];
        bins[(size_t)gdst[b] + (i - loff[b])] = recs[i];
    }
}

// Build: one block per bucket; contiguous record range; ELL+deg+cnt in LDS,
// burst-write. Also zeroes aggf rows of ITS OWN overflowed nodes (exclusive).
__global__ void __launch_bounds__(256)
k_build(const uint2* __restrict__ bins, const int* __restrict__ btot,
        unsigned int* __restrict__ ell, float* __restrict__ deg,
        int* __restrict__ cnt, int2* __restrict__ ovf, int* __restrict__ ovf_cnt,
        float* __restrict__ aggf, int n, int nb) {
    int b = blockIdx.x;
    int c0 = b << 8;
    int nn = n - c0; if (nn > BND) nn = BND;
    __shared__ unsigned int tile[BND * CAP];   // 16 KB
    __shared__ float sdeg[BND];
    __shared__ int scnt[BND];
    __shared__ int bb[NBMAX];
    __shared__ int ovl[BND];
    __shared__ int novloc;
    int tid = threadIdx.x;
    sdeg[tid] = 0.0f; scnt[tid] = 0;
    if (tid == 0) novloc = 0;
    for (int i = tid; i < BND * CAP; i += 256) tile[i] = 0u;
    scan512_to_lds(btot, bb, nb, tid);
    __syncthreads();
    int s0 = bb[b], tot = btot[b];
    for (int i = tid; i < tot; i += 256) {
        uint2 rec = bins[(size_t)s0 + i];
        int cl = (int)((rec.y >> 15) & (BND - 1));
        unsigned int w15 = rec.y & 0x7FFFu;
        atomicAdd(&sdeg[cl], f15dec(w15));
        int slot = atomicAdd(&scnt[cl], 1);
        unsigned int p = (rec.x << 15) | w15;
        if (slot < CAP) {
            tile[cl * CAP + slot] = p;
        } else {
            int oi = atomicAdd(ovf_cnt, 1);
            ovf[oi] = make_int2(c0 + cl, (int)p);
        }
    }
    __syncthreads();
    for (int i = tid; i < nn * CAP; i += 256)
        ell[(size_t)c0 * CAP + i] = tile[i];
    if (tid < nn) {
        deg[c0 + tid] = sdeg[tid] + 1.0f;   // raw degree incl. self-loop
        cnt[c0 + tid] = scnt[tid];
        if (scnt[tid] > CAP) { int k = atomicAdd(&novloc, 1); ovl[k] = tid; }
    }
    __syncthreads();
    int nov = novloc;
    for (int k = 0; k < nov; ++k) {
        if (tid < NIN) aggf[(size_t)(c0 + ovl[k]) * NIN + tid] = 0.0f;
    }
}

// Replay node-degree-overflow edges (slot >= CAP, ~hundreds) into f32 aggf.
__global__ void k_ovf(const int2* __restrict__ ovf, const int* __restrict__ ovf_cnt,
                      const float* __restrict__ deg, const ushort* __restrict__ x16,
                      float* __restrict__ aggf) {
    int nov = *ovf_cnt;
    int wid = (int)((blockIdx.x * (size_t)blockDim.x + threadIdx.x) >> 6);
    int lane = threadIdx.x & 63;
    int nw = (int)((gridDim.x * (size_t)blockDim.x) >> 6);
    for (int i = wid; i < nov; i += nw) {
        int2 ov = ovf[i];
        int c = ov.x;
        unsigned int p = (unsigned int)ov.y;
        int r = (int)(p >> 15);
        float w = f15dec(p & 0x7FFFu) * rsqrtf(deg[r]) * rsqrtf(deg[c]);
        atomicAdd(&aggf[(size_t)c * NIN + lane], w * bf2f(x16[(size_t)r * NIN + lane]));
    }
}

// Gather: 8 nodes/wave, 8 lanes/node, uint4 (8 bf16) per lane.
// One VMEM instruction fetches a slot's source rows for all 8 nodes.
__global__ void __launch_bounds__(256)
k_gather(const ushort* __restrict__ x16, const float* __restrict__ deg,
         const int* __restrict__ cnt, const unsigned int* __restrict__ ell,
         const float* __restrict__ aggf, ushort* __restrict__ agg16,
         const float* __restrict__ Wp, const float* __restrict__ bp,
         float* __restrict__ score, int n) {
    int wid = (int)((blockIdx.x * (size_t)blockDim.x + threadIdx.x) >> 6);
    int lane = threadIdx.x & 63;
    int o = lane >> 3, l = lane & 7;
    int c0 = wid * 8;
    if (c0 >= n) return;
    int c = c0 + o;
    bool valid = c < n;
    int cc = valid ? c : (n - 1);

    int cr = cnt[cc];
    int m = valid ? (cr < CAP ? cr : CAP) : 0;
    float di = rsqrtf(deg[cc]);

    // lane l holds slots 2l, 2l+1 of its node's ELL row (wave: 8 nodes x 64B)
    const uint2* ell2 = (const uint2*)ell;
    uint2 pe = ell2[(size_t)cc * 8 + l];
    int pr0 = (int)(pe.x >> 15);
    float pw0 = f15dec(pe.x & 0x7FFFu) * rsqrtf(deg[pr0]);
    int pr1 = (int)(pe.y >> 15);
    float pw1 = f15dec(pe.y & 0x7FFFu) * rsqrtf(deg[pr1]);

    const uint4* xr4 = (const uint4*)x16;   // row = 8 x uint4
    uint4 xs = xr4[(size_t)cc * 8 + l];
    float a0 = di * bflo(xs.x), a1 = di * bfhi(xs.x);
    float a2 = di * bflo(xs.y), a3 = di * bfhi(xs.y);
    float a4 = di * bflo(xs.z), a5 = di * bfhi(xs.z);
    float a6 = di * bflo(xs.w), a7 = di * bfhi(xs.w);

    int base = lane & 56;   // first lane of this 8-lane group
    #pragma unroll
    for (int k = 0; k < 8; ++k) {
        int rk = __shfl((k & 1) ? pr1 : pr0, base + (k >> 1));
        float wk = __shfl((k & 1) ? pw1 : pw0, base + (k >> 1));
        bool v = k < m;
        int r = v ? rk : 0;
        float w = v ? wk : 0.0f;
        uint4 xr = xr4[(size_t)r * 8 + l];
        a0 = fmaf(w, bflo(xr.x), a0); a1 = fmaf(w, bfhi(xr.x), a1);
        a2 = fmaf(w, bflo(xr.y), a2); a3 = fmaf(w, bfhi(xr.y), a3);
        a4 = fmaf(w, bflo(xr.z), a4); a5 = fmaf(w, bfhi(xr.z), a5);
        a6 = fmaf(w, bflo(xr.w), a6); a7 = fmaf(w, bfhi(xr.w), a7);
    }
    if (__any(m > 8)) {
        #pragma unroll
        for (int k = 8; k < CAP; ++k) {
            int rk = __shfl((k & 1) ? pr1 : pr0, base + (k >> 1));
            float wk = __shfl((k & 1) ? pw1 : pw0, base + (k >> 1));
            bool v = k < m;
            int r = v ? rk : 0;
            float w = v ? wk : 0.0f;
            uint4 xr = xr4[(size_t)r * 8 + l];
            a0 = fmaf(w, bflo(xr.x), a0); a1 = fmaf(w, bfhi(xr.x), a1);
            a2 = fmaf(w, bflo(xr.y), a2); a3 = fmaf(w, bfhi(xr.y), a3);
            a4 = fmaf(w, bflo(xr.z), a4); a5 = fmaf(w, bfhi(xr.z), a5);
            a6 = fmaf(w, bflo(xr.w), a6); a7 = fmaf(w, bfhi(xr.w), a7);
        }
    }
    a0 *= di; a1 *= di; a2 *= di; a3 *= di;
    a4 *= di; a5 *= di; a6 *= di; a7 *= di;

    if (valid && cr > CAP) {
        const float4* af4 = (const float4*)aggf;
        float4 f0 = af4[(size_t)cc * 16 + 2 * l];
        float4 f1 = af4[(size_t)cc * 16 + 2 * l + 1];
        a0 += f0.x; a1 += f0.y; a2 += f0.z; a3 += f0.w;
        a4 += f1.x; a5 += f1.y; a6 += f1.z; a7 += f1.w;
    }

    if (valid) {
        uint4 ho;
        ho.x = pack2bf(a0, a1); ho.y = pack2bf(a2, a3);
        ho.z = pack2bf(a4, a5); ho.w = pack2bf(a6, a7);
        ((uint4*)agg16)[(size_t)cc * 8 + l] = ho;
    }

    const float4* wp4 = (const float4*)Wp;
    float4 w0 = wp4[2 * l], w1 = wp4[2 * l + 1];
    float part = a0 * w0.x + a1 * w0.y + a2 * w0.z + a3 * w0.w
               + a4 * w1.x + a5 * w1.y + a6 * w1.z + a7 * w1.w;
    part += __shfl_xor(part, 1);
    part += __shfl_xor(part, 2);
    part += __shfl_xor(part, 4);
    if (l == 0 && valid) score[c] = part + bp[0];
}

// POOL_SPLIT blocks per graph. Fused per-graph softmax; W column in 16 NAMED
// float4s; node agg row staged via LDS broadcast; 4 FMA chains; prefetch.
#define WLOAD(i) float4 wq##i = make_float4(We[(4*(i)+0)*NIN+lane], We[(4*(i)+1)*NIN+lane], \
                                            We[(4*(i)+2)*NIN+lane], We[(4*(i)+3)*NIN+lane]);
#define WSTEP(i) { float4 av = *(const float4*)&als[wv][4*(i)]; \
    e0 = fmaf(av.x, wq##i.x, e0); e1 = fmaf(av.y, wq##i.y, e1); \
    e2 = fmaf(av.z, wq##i.z, e2); e3 = fmaf(av.w, wq##i.w, e3); }

__global__ void __launch_bounds__(256)
k_pool(const ushort* __restrict__ agg16, const float* __restrict__ score,
       const float* __restrict__ We, const float* __restrict__ be,
       const int* __restrict__ gstart, const int* __restrict__ gend,
       float* __restrict__ out) {
    int g = blockIdx.x / POOL_SPLIT;
    int p = blockIdx.x % POOL_SPLIT;
    int tid = threadIdx.x;
    int wv = tid >> 6, lane = tid & 63;
    int s = gstart[g], e = gend[g];

    __shared__ float red[4];
    __shared__ float bc;

    float mx = -3.402823466e38f;
    for (int i = s + tid; i < e; i += 256) mx = fmaxf(mx, score[i]);
    #pragma unroll
    for (int off = 32; off > 0; off >>= 1) mx = fmaxf(mx, __shfl_xor(mx, off));
    if (lane == 0) red[wv] = mx;
    __syncthreads();
    if (tid == 0) bc = fmaxf(fmaxf(red[0], red[1]), fmaxf(red[2], red[3]));
    __syncthreads();
    float m = bc;
    __syncthreads();

    float sm = 0.0f;
    for (int i = s + tid; i < e; i += 256) sm += __expf(score[i] - m);
    sm = wave_reduce_sum(sm);
    if (lane == 0) red[wv] = sm;
    __syncthreads();
    if (tid == 0) bc = red[0] + red[1] + red[2] + red[3];
    __syncthreads();
    float invz = (bc > 0.0f) ? 1.0f / bc : 0.0f;

    WLOAD(0) WLOAD(1) WLOAD(2) WLOAD(3) WLOAD(4) WLOAD(5) WLOAD(6) WLOAD(7)
    WLOAD(8) WLOAD(9) WLOAD(10) WLOAD(11) WLOAD(12) WLOAD(13) WLOAD(14) WLOAD(15)
    float bj = be[lane];

    __shared__ float als[4][NIN];
    __shared__ float part[4][NIN];

    const int stride = POOL_SPLIT * 4;
    int n = s + p * 4 + wv;
    float acc = 0.0f;

    float a_cur = 0.0f, sw_cur = 0.0f;
    if (n < e) {
        a_cur = bf2f(agg16[(size_t)n * NIN + lane]);
        sw_cur = __expf(score[n] - m) * invz;
    }
    while (n < e) {
        int nn = n + stride;
        bool vn = nn < e;
        int ni = vn ? nn : n;
        float a_nxt = bf2f(agg16[(size_t)ni * NIN + lane]);   // prefetch
        float sw_nxt = __expf(score[ni] - m) * invz;

        als[wv][lane] = a_cur;
        float e0 = bj, e1 = 0.0f, e2 = 0.0f, e3 = 0.0f;
        WSTEP(0) WSTEP(1) WSTEP(2) WSTEP(3) WSTEP(4) WSTEP(5) WSTEP(6) WSTEP(7)
        WSTEP(8) WSTEP(9) WSTEP(10) WSTEP(11) WSTEP(12) WSTEP(13) WSTEP(14) WSTEP(15)
        float emb = fmaxf(e0 + e1 + e2 + e3, 0.0f);
        acc = fmaf(sw_cur, emb, acc);

        a_cur = a_nxt; sw_cur = sw_nxt;
        n = nn;
    }
    part[wv][lane] = acc;
    __syncthreads();
    if (wv == 0) {
        float r = part[0][lane] + part[1][lane] + part[2][lane] + part[3][lane];
        atomicAdd(&out[(size_t)g * NIN + lane], r);
    }
}

extern "C" void kernel_launch(void* const* d_in, const int* in_sizes, int n_in,
                              void* d_out, int out_size, void* d_ws, size_t ws_size,
                              hipStream_t stream) {
    const float* x  = (const float*)d_in[0];
    const float* We = (const float*)d_in[1];
    const float* be = (const float*)d_in[2];
    const float* Wp = (const float*)d_in[3];
    const float* bp = (const float*)d_in[4];
    const float* ew = (const float*)d_in[5];
    const int* eidx = (const int*)d_in[6];
    const int* seg  = (const int*)d_in[7];

    int N = in_sizes[0] / NIN;
    int E = in_sizes[5];
    const int* row = eidx;
    const int* col = eidx + E;
    int nb   = (N + BND - 1) / BND;       // 391
    int nblk = (E + CHUNK - 1) / CHUNK;   // 391

    char* w = (char*)d_ws;
    auto alloc = [&](size_t bytes) {
        char* p = w;
        w += (bytes + 255) & ~(size_t)255;
        return p;
    };
    float*          aggf    = (float*)alloc((size_t)N * NIN * sizeof(float));
    unsigned short* x16     = (unsigned short*)alloc((size_t)N * NIN * sizeof(short));
    unsigned short* agg16   = (unsigned short*)alloc((size_t)N * NIN * sizeof(short));
    float*          deg     = (float*)alloc((size_t)N * sizeof(float));
    int*            cnt     = (int*)  alloc((size_t)N * sizeof(int));
    unsigned int*   ell     = (unsigned int*)alloc((size_t)N * CAP * sizeof(unsigned int));
    uint2*          bins    = (uint2*)alloc((size_t)E * sizeof(uint2));
    int*            ghist   = (int*)  alloc((size_t)nblk * nb * sizeof(int));
    int*            btot    = (int*)  alloc((size_t)nb * sizeof(int));
    int2*           ovf     = (int2*) alloc((size_t)(E / 4) * sizeof(int2));
    int*            ovf_cnt = (int*)  alloc(256);
    float*          score   = (float*)alloc((size_t)N * sizeof(float));
    int*            gstart  = (int*)  alloc(GSEG * sizeof(int));
    int*            gend    = (int*)  alloc(GSEG * sizeof(int));
    float* out = (float*)d_out;

    int b = 256;
    int g_prep   = (N * (NIN / 4) + b - 1) / b;   // 6250 >= nblk
    int nwaves   = (N + 7) / 8;
    int g_gather = (nwaves + 3) / 4;

    k_prep<<<g_prep, b, 0, stream>>>((ushort4*)x16, (const float4*)x, out, gstart,
                                     gend, ovf_cnt, col, ghist, N, E, nb, nblk);
    k_scanA<<<nb, 64, 0, stream>>>(ghist, btot, seg, gstart, gend, nblk, nb, N);
    k_scatter<<<nblk, b, 0, stream>>>(row, col, ew, ghist, btot, bins, E, nb);
    k_build<<<nb, b, 0, stream>>>(bins, btot, ell, deg, cnt, ovf, ovf_cnt, aggf, N, nb);
    k_ovf<<<64, b, 0, stream>>>(ovf, ovf_cnt, deg, x16, aggf);
    k_gather<<<g_gather, b, 0, stream>>>(x16, deg, cnt, ell, aggf, agg16, Wp, bp, score, N);
    k_pool<<<GSEG * POOL_SPLIT, b, 0, stream>>>(agg16, score, We, be, gstart, gend, out);
}